// Round 1
// baseline (2214.935 us; speedup 1.0000x reference)
//
#include <hip/hip_runtime.h>
#include <cstddef>
#include <cstdint>

// Problem constants
constexpr int CB   = 2;
constexpr int CL   = 2048;
constexpr int CD   = 512;
constexpr int CH   = 8;
constexpr int CDK  = 64;
constexpr int CNL  = 2;
constexpr int CDFF = 1024;
constexpr float CEPS = 1e-3f;
constexpr float INV_TEMPER = 0.044194173824159216f;  // 1/sqrt(512)

// ---------------- repack wq/wk/wv (NL,H,D,DK) -> (NL, 1536, D) row-major (N,K) ----------------
__global__ __launch_bounds__(256) void repack_qkv(const float* __restrict__ wq,
                                                  const float* __restrict__ wk,
                                                  const float* __restrict__ wv,
                                                  float* __restrict__ dst) {
  int i = blockIdx.x * 256 + threadIdx.x;   // total CNL*1536*CD = 1,572,864 = 6144*256
  int d = i & (CD - 1);
  int rest = i >> 9;            // l*1536 + n
  int n = rest % 1536;
  int l = rest / 1536;
  int which = n >> 9;           // 0=q 1=k 2=v
  int r = n & 511;
  int hh = r >> 6;
  int kk = r & 63;
  const float* src = (which == 0) ? wq : (which == 1) ? wk : wv;
  dst[i] = src[(((size_t)l * CH + hh) * CD + d) * CDK + kk];
}

// ---------------- x + pos (broadcast over batch) ----------------
__global__ __launch_bounds__(256) void add_pos(const float4* __restrict__ x,
                                               const float4* __restrict__ pos,
                                               float4* __restrict__ out) {
  int i = blockIdx.x * 256 + threadIdx.x;        // < CB*CL*CD/4 = 524288
  float4 a = x[i];
  float4 p = pos[i & (CL * CD / 4 - 1)];
  out[i] = make_float4(a.x + p.x, a.y + p.y, a.z + p.z, a.w + p.w);
}

// ---------------- f32 GEMM: C[M,N] = A[M,K] * W[N,K]^T (+bias)(+relu) ----------------
// BM=BN=128, BK=32, 256 threads, 8x8 per thread.
template<bool BIAS, bool RELU>
__global__ __launch_bounds__(256) void gemm_f32(const float* __restrict__ A,
                                                const float* __restrict__ W,
                                                const float* __restrict__ bias,
                                                float* __restrict__ C,
                                                int M, int N, int K) {
  __shared__ float As[32][132];   // [k][m], stride 132 (16B-aligned rows, low conflicts)
  __shared__ float Ws[32][132];   // [k][n]
  const int t  = threadIdx.x;
  const int tx = t & 15, ty = t >> 4;
  const int m0 = blockIdx.y * 128, n0 = blockIdx.x * 128;
  const int srow = t >> 1, sc0 = (t & 1) * 16;
  const float* aptr = A + (size_t)(m0 + srow) * K + sc0;
  const float* wptr = W + (size_t)(n0 + srow) * K + sc0;
  float c[8][8] = {};
  for (int kb = 0; kb < K; kb += 32) {
#pragma unroll
    for (int i = 0; i < 16; i += 4) {
      float4 av = *(const float4*)(aptr + kb + i);
      As[sc0 + i + 0][srow] = av.x;
      As[sc0 + i + 1][srow] = av.y;
      As[sc0 + i + 2][srow] = av.z;
      As[sc0 + i + 3][srow] = av.w;
      float4 wv = *(const float4*)(wptr + kb + i);
      Ws[sc0 + i + 0][srow] = wv.x;
      Ws[sc0 + i + 1][srow] = wv.y;
      Ws[sc0 + i + 2][srow] = wv.z;
      Ws[sc0 + i + 3][srow] = wv.w;
    }
    __syncthreads();
#pragma unroll 8
    for (int kk = 0; kk < 32; ++kk) {
      float a[8], w[8];
      *(float4*)&a[0] = *(const float4*)&As[kk][ty * 8];
      *(float4*)&a[4] = *(const float4*)&As[kk][ty * 8 + 4];
      *(float4*)&w[0] = *(const float4*)&Ws[kk][tx * 8];
      *(float4*)&w[4] = *(const float4*)&Ws[kk][tx * 8 + 4];
#pragma unroll
      for (int i = 0; i < 8; ++i)
#pragma unroll
        for (int j = 0; j < 8; ++j)
          c[i][j] = fmaf(a[i], w[j], c[i][j]);
    }
    __syncthreads();
  }
  float bb[8];
  if (BIAS) {
    *(float4*)&bb[0] = *(const float4*)(bias + n0 + tx * 8);
    *(float4*)&bb[4] = *(const float4*)(bias + n0 + tx * 8 + 4);
  }
#pragma unroll
  for (int i = 0; i < 8; ++i) {
    float o[8];
#pragma unroll
    for (int j = 0; j < 8; ++j) {
      float v = c[i][j];
      if (BIAS) v += bb[j];
      if (RELU) v = fmaxf(v, 0.f);
      o[j] = v;
    }
    size_t off = (size_t)(m0 + ty * 8 + i) * N + n0 + tx * 8;
    *(float4*)&C[off]     = make_float4(o[0], o[1], o[2], o[3]);
    *(float4*)&C[off + 4] = make_float4(o[4], o[5], o[6], o[7]);
  }
}

// ---------------- fused flash-style attention (f32) ----------------
// qkv: (B, L, 1536) with q cols [0,512), k [512,1024), v [1024,1536); head h at h*64.
// Block: 256 threads (4 waves). Q-tile = 32 rows (8 per wave), KV-tile = 64.
__global__ __launch_bounds__(256) void attn_f32(const float* __restrict__ qkv,
                                                float* __restrict__ out) {
  const int blk  = blockIdx.x;           // b*512 + h*64 + qt  (qt in [0,64))
  const int qt   = blk & 63;
  const int h    = (blk >> 6) & 7;
  const int b    = blk >> 9;
  const int t    = threadIdx.x;
  const int w    = t >> 6;
  const int lane = t & 63;
  __shared__ float Qs[32][64];   // reads are wave-broadcast: no pad needed
  __shared__ float Ks[64][68];   // pad 4: row base 16B-aligned, col reads 2-way max
  __shared__ float Vs[64][68];
  __shared__ float Ps[32][64];   // writes lane-major (2-way), reads broadcast
  const float* qbase = qkv + (size_t)b * CL * 1536 + h * 64;
  const float* kbase = qbase + 512;
  const float* vbase = qbase + 1024;
  // stage Q tile (32 rows x 64)
  {
    const int row = t >> 3, c0 = (t & 7) * 8;
    const float* src = qbase + (size_t)(qt * 32 + row) * 1536 + c0;
    float4 v0 = *(const float4*)src;
    float4 v1 = *(const float4*)(src + 4);
    Qs[row][c0 + 0] = v0.x; Qs[row][c0 + 1] = v0.y;
    Qs[row][c0 + 2] = v0.z; Qs[row][c0 + 3] = v0.w;
    Qs[row][c0 + 4] = v1.x; Qs[row][c0 + 5] = v1.y;
    Qs[row][c0 + 6] = v1.z; Qs[row][c0 + 7] = v1.w;
  }
  float m[8], lsum[8], o[8];
#pragma unroll
  for (int q = 0; q < 8; ++q) { m[q] = -1e30f; lsum[q] = 0.f; o[q] = 0.f; }
  __syncthreads();

  for (int jt = 0; jt < CL / 64; ++jt) {
    // stage K,V tiles (64 rows x 64)
    {
      const int row = t >> 2, c0 = (t & 3) * 16;
      const float* ks = kbase + (size_t)(jt * 64 + row) * 1536 + c0;
      const float* vs = vbase + (size_t)(jt * 64 + row) * 1536 + c0;
#pragma unroll
      for (int i = 0; i < 16; i += 4) {
        float4 kv = *(const float4*)(ks + i);
        Ks[row][c0 + i + 0] = kv.x; Ks[row][c0 + i + 1] = kv.y;
        Ks[row][c0 + i + 2] = kv.z; Ks[row][c0 + i + 3] = kv.w;
        float4 vv = *(const float4*)(vs + i);
        Vs[row][c0 + i + 0] = vv.x; Vs[row][c0 + i + 1] = vv.y;
        Vs[row][c0 + i + 2] = vv.z; Vs[row][c0 + i + 3] = vv.w;
      }
    }
    __syncthreads();

    // scores: lane = j (0..63), each wave owns 8 q rows
    float s[8] = {};
#pragma unroll 4
    for (int k4 = 0; k4 < 64; k4 += 4) {
      float4 kv = *(const float4*)&Ks[lane][k4];
#pragma unroll
      for (int q = 0; q < 8; ++q) {
        float4 qv = *(const float4*)&Qs[w * 8 + q][k4];
        s[q] = fmaf(qv.x, kv.x, s[q]);
        s[q] = fmaf(qv.y, kv.y, s[q]);
        s[q] = fmaf(qv.z, kv.z, s[q]);
        s[q] = fmaf(qv.w, kv.w, s[q]);
      }
    }
    // online softmax per q row (all-lane reductions over 64 lanes)
#pragma unroll
    for (int q = 0; q < 8; ++q) {
      float sv = s[q] * INV_TEMPER;
      float mx = sv;
#pragma unroll
      for (int off = 32; off > 0; off >>= 1) mx = fmaxf(mx, __shfl_xor(mx, off));
      float mnew = fmaxf(m[q], mx);
      float p = __expf(sv - mnew);
      float ps = p;
#pragma unroll
      for (int off = 32; off > 0; off >>= 1) ps += __shfl_xor(ps, off);
      float scale = __expf(m[q] - mnew);
      lsum[q] = lsum[q] * scale + ps;
      o[q] *= scale;
      m[q] = mnew;
      Ps[w * 8 + q][lane] = p;   // same-wave write, read below (lgkmcnt-ordered)
    }
    // PV: lane = v (0..63)
#pragma unroll
    for (int q = 0; q < 8; ++q) {
      float acc = 0.f;
#pragma unroll 4
      for (int j4 = 0; j4 < 64; j4 += 4) {
        float4 pv = *(const float4*)&Ps[w * 8 + q][j4];
        acc = fmaf(pv.x, Vs[j4 + 0][lane], acc);
        acc = fmaf(pv.y, Vs[j4 + 1][lane], acc);
        acc = fmaf(pv.z, Vs[j4 + 2][lane], acc);
        acc = fmaf(pv.w, Vs[j4 + 3][lane], acc);
      }
      o[q] += acc;
    }
    __syncthreads();   // protect Ks/Vs before next stage
  }
  // write out: (B, L, H*DK) concat-head layout
#pragma unroll
  for (int q = 0; q < 8; ++q) {
    out[((size_t)b * CL + qt * 32 + w * 8 + q) * CD + h * 64 + lane] = o[q] / lsum[q];
  }
}

// ---------------- fused residual add + LayerNorm (torch.std ddof=1, /(sigma+eps)) ----------------
__global__ __launch_bounds__(256) void add_ln(const float* __restrict__ u,
                                              const float* __restrict__ v,
                                              const float* __restrict__ ga,
                                              const float* __restrict__ gb,
                                              float* __restrict__ out) {
  const int row  = blockIdx.x * 4 + (threadIdx.x >> 6);
  const int lane = threadIdx.x & 63;
  const size_t base = (size_t)row * CD;
  float4 u0 = *(const float4*)(u + base + lane * 4);
  float4 v0 = *(const float4*)(v + base + lane * 4);
  float4 u1 = *(const float4*)(u + base + 256 + lane * 4);
  float4 v1 = *(const float4*)(v + base + 256 + lane * 4);
  float z[8] = { u0.x + v0.x, u0.y + v0.y, u0.z + v0.z, u0.w + v0.w,
                 u1.x + v1.x, u1.y + v1.y, u1.z + v1.z, u1.w + v1.w };
  float sum = 0.f, sq = 0.f;
#pragma unroll
  for (int i = 0; i < 8; ++i) { sum += z[i]; sq = fmaf(z[i], z[i], sq); }
#pragma unroll
  for (int off = 32; off > 0; off >>= 1) {
    sum += __shfl_xor(sum, off);
    sq  += __shfl_xor(sq, off);
  }
  float mean = sum * (1.f / CD);
  float var  = fmaxf((sq - (float)CD * mean * mean) * (1.f / (CD - 1)), 0.f);
  float inv  = 1.f / (sqrtf(var) + CEPS);
  float4 a0 = *(const float4*)(ga + lane * 4);
  float4 a1 = *(const float4*)(ga + 256 + lane * 4);
  float4 b0 = *(const float4*)(gb + lane * 4);
  float4 b1 = *(const float4*)(gb + 256 + lane * 4);
  float4 y0 = make_float4(fmaf((z[0] - mean) * inv, a0.x, b0.x),
                          fmaf((z[1] - mean) * inv, a0.y, b0.y),
                          fmaf((z[2] - mean) * inv, a0.z, b0.z),
                          fmaf((z[3] - mean) * inv, a0.w, b0.w));
  float4 y1 = make_float4(fmaf((z[4] - mean) * inv, a1.x, b1.x),
                          fmaf((z[5] - mean) * inv, a1.y, b1.y),
                          fmaf((z[6] - mean) * inv, a1.z, b1.z),
                          fmaf((z[7] - mean) * inv, a1.w, b1.w));
  *(float4*)(out + base + lane * 4)       = y0;
  *(float4*)(out + base + 256 + lane * 4) = y1;
}

extern "C" void kernel_launch(void* const* d_in, const int* in_sizes, int n_in,
                              void* d_out, int out_size, void* d_ws, size_t ws_size,
                              hipStream_t stream) {
  (void)in_sizes; (void)n_in; (void)out_size; (void)ws_size;
  const float* x    = (const float*)d_in[0];
  const float* pos  = (const float*)d_in[1];
  const float* wq   = (const float*)d_in[2];
  const float* wk   = (const float*)d_in[3];
  const float* wv   = (const float*)d_in[4];
  const float* ln1a = (const float*)d_in[5];
  const float* ln1b = (const float*)d_in[6];
  const float* w1   = (const float*)d_in[7];
  const float* b1   = (const float*)d_in[8];
  const float* w2   = (const float*)d_in[9];
  const float* b2   = (const float*)d_in[10];
  const float* ln2a = (const float*)d_in[11];
  const float* ln2b = (const float*)d_in[12];

  float* ws = (float*)d_ws;
  const size_t NTOK = (size_t)CB * CL;          // 4096
  float* xw   = ws;                             // NTOK*CD      (current block input)
  float* x1   = xw + NTOK * CD;                 // NTOK*CD      (LN1 output)
  float* qkvb = x1 + NTOK * CD;                 // NTOK*1536
  float* attb = qkvb + NTOK * 1536;             // NTOK*CD
  float* wqkv = attb + NTOK * CD;               // CNL*1536*CD
  // FFN buffers reuse the qkv region (qkv dead after attn): total ws = 56.6 MB
  float* ff1  = qkvb;                           // NTOK*CDFF
  float* ff2  = qkvb + NTOK * CDFF;             // NTOK*CD

  repack_qkv<<<6144, 256, 0, stream>>>(wq, wk, wv, wqkv);
  add_pos<<<2048, 256, 0, stream>>>((const float4*)x, (const float4*)pos, (float4*)xw);

  for (int l = 0; l < CNL; ++l) {
    gemm_f32<false, false><<<dim3(12, 32), 256, 0, stream>>>(
        xw, wqkv + (size_t)l * 1536 * CD, nullptr, qkvb, 4096, 1536, 512);
    attn_f32<<<1024, 256, 0, stream>>>(qkvb, attb);
    add_ln<<<1024, 256, 0, stream>>>(attb, xw, ln1a + l * CD, ln1b + l * CD, x1);
    gemm_f32<true, true><<<dim3(8, 32), 256, 0, stream>>>(
        x1, w1 + (size_t)l * CDFF * CD, b1 + l * CDFF, ff1, 4096, 1024, 512);
    gemm_f32<true, false><<<dim3(4, 32), 256, 0, stream>>>(
        ff1, w2 + (size_t)l * CD * CDFF, b2 + l * CD, ff2, 4096, 512, 1024);
    float* dst = (l == CNL - 1) ? (float*)d_out : xw;
    add_ln<<<1024, 256, 0, stream>>>(ff2, x1, ln2a + l * CD, ln2b + l * CD, dst);
  }
}

// Round 2
// 815.455 us; speedup vs baseline: 2.7162x; 2.7162x over previous
//
#include <hip/hip_runtime.h>
#include <cstddef>
#include <cstdint>

typedef unsigned int u32;
typedef unsigned short u16;

constexpr int CB = 2, CL = 2048, CD = 512, CH = 8, CNL = 2, CDFF = 1024;
constexpr float CEPS = 1e-3f;
constexpr float INV_TEMPER = 0.044194173824159216f;  // 1/sqrt(512)

typedef __attribute__((ext_vector_type(16))) float f32x16v;
typedef __attribute__((ext_vector_type(8))) short s16x8;

union B128 { s16x8 v; uint4 q; u32 u[4]; };

__device__ inline u16 f2bf(float f) {
  union { float f; u32 u; } x; x.f = f;
  u32 r = x.u + 0x7fffu + ((x.u >> 16) & 1u);
  return (u16)(r >> 16);
}
__device__ inline u32 pk2rne(float a, float b) {
  return (u32)f2bf(a) | ((u32)f2bf(b) << 16);
}
__device__ inline u32 pk2trunc(float a, float b) {  // P in [0,1]: truncation ok
  union { float f; u32 u; } xa, xb; xa.f = a; xb.f = b;
  return (xa.u >> 16) | (xb.u & 0xffff0000u);
}

// ---------------- repack wq/wk/wv (NL,H,D,DK) -> (NL, 1536, D) row-major (N,K) ----------------
__global__ __launch_bounds__(256) void repack_qkv(const float* __restrict__ wq,
                                                  const float* __restrict__ wk,
                                                  const float* __restrict__ wv,
                                                  float* __restrict__ dst) {
  int i = blockIdx.x * 256 + threadIdx.x;
  int d = i & (CD - 1);
  int rest = i >> 9;
  int n = rest % 1536;
  int l = rest / 1536;
  int which = n >> 9;
  int r = n & 511;
  int hh = r >> 6;
  int kk = r & 63;
  const float* src = (which == 0) ? wq : (which == 1) ? wk : wv;
  dst[i] = src[(((size_t)l * CH + hh) * CD + d) * 64 + kk];
}

// ---------------- x + pos ----------------
__global__ __launch_bounds__(256) void add_pos(const float4* __restrict__ x,
                                               const float4* __restrict__ pos,
                                               float4* __restrict__ out) {
  int i = blockIdx.x * 256 + threadIdx.x;
  float4 a = x[i];
  float4 p = pos[i & (CL * CD / 4 - 1)];
  out[i] = make_float4(a.x + p.x, a.y + p.y, a.z + p.z, a.w + p.w);
}

// ---------------- f32 GEMM: C[M,N] = A[M,K] * W[N,K]^T ----------------
// MODE 0: f32 out (+bias)(+relu).  MODE 1: QKV epilogue -> bf16 Q,K [bh][L][64] (Q scaled), V^T [bh][64][L]
template<int MODE, bool BIAS, bool RELU>
__global__ __launch_bounds__(256) void gemm_f32(const float* __restrict__ A,
                                                const float* __restrict__ W,
                                                const float* __restrict__ bias,
                                                float* __restrict__ C,
                                                u16* __restrict__ qbuf,
                                                u16* __restrict__ kbuf,
                                                u16* __restrict__ vtbuf,
                                                int M, int N, int K) {
  __shared__ float As[32][132];
  __shared__ float Ws[32][132];
  const int t  = threadIdx.x;
  const int tx = t & 15, ty = t >> 4;
  const int m0 = blockIdx.y * 128, n0 = blockIdx.x * 128;
  const int srow = t >> 1, sc0 = (t & 1) * 16;
  const float* aptr = A + (size_t)(m0 + srow) * K + sc0;
  const float* wptr = W + (size_t)(n0 + srow) * K + sc0;
  float c[8][8] = {};
  for (int kb = 0; kb < K; kb += 32) {
#pragma unroll
    for (int i = 0; i < 16; i += 4) {
      float4 av = *(const float4*)(aptr + kb + i);
      As[sc0 + i + 0][srow] = av.x;
      As[sc0 + i + 1][srow] = av.y;
      As[sc0 + i + 2][srow] = av.z;
      As[sc0 + i + 3][srow] = av.w;
      float4 wv = *(const float4*)(wptr + kb + i);
      Ws[sc0 + i + 0][srow] = wv.x;
      Ws[sc0 + i + 1][srow] = wv.y;
      Ws[sc0 + i + 2][srow] = wv.z;
      Ws[sc0 + i + 3][srow] = wv.w;
    }
    __syncthreads();
#pragma unroll 8
    for (int kk = 0; kk < 32; ++kk) {
      float a[8], w[8];
      *(float4*)&a[0] = *(const float4*)&As[kk][ty * 8];
      *(float4*)&a[4] = *(const float4*)&As[kk][ty * 8 + 4];
      *(float4*)&w[0] = *(const float4*)&Ws[kk][tx * 8];
      *(float4*)&w[4] = *(const float4*)&Ws[kk][tx * 8 + 4];
#pragma unroll
      for (int i = 0; i < 8; ++i)
#pragma unroll
        for (int j = 0; j < 8; ++j)
          c[i][j] = fmaf(a[i], w[j], c[i][j]);
    }
    __syncthreads();
  }
  if (MODE == 1) {
    const int n_base = n0 + tx * 8;
    const int region = n_base >> 9;           // 0=q 1=k 2=v
    const int hh = (n_base >> 6) & 7;
    const int dk0 = n_base & 63;
    const int bb = m0 >> 11;
    const int l0 = (m0 & 2047) + ty * 8;
    const int bhh = bb * 8 + hh;
    if (region <= 1) {
      const float mul = (region == 0) ? INV_TEMPER : 1.f;
      u16* dst = (region == 0 ? qbuf : kbuf) + ((size_t)bhh * 2048 + l0) * 64 + dk0;
#pragma unroll
      for (int i = 0; i < 8; ++i) {
        uint4 pk;
        pk.x = pk2rne(c[i][0] * mul, c[i][1] * mul);
        pk.y = pk2rne(c[i][2] * mul, c[i][3] * mul);
        pk.z = pk2rne(c[i][4] * mul, c[i][5] * mul);
        pk.w = pk2rne(c[i][6] * mul, c[i][7] * mul);
        *(uint4*)(dst + (size_t)i * 64) = pk;
      }
    } else {
      u16* dst = vtbuf + ((size_t)bhh * 64 + dk0) * 2048 + l0;
#pragma unroll
      for (int j = 0; j < 8; ++j) {
        uint4 pk;
        pk.x = pk2rne(c[0][j], c[1][j]);
        pk.y = pk2rne(c[2][j], c[3][j]);
        pk.z = pk2rne(c[4][j], c[5][j]);
        pk.w = pk2rne(c[6][j], c[7][j]);
        *(uint4*)(dst + (size_t)j * 2048) = pk;
      }
    }
    return;
  }
  float bb2[8];
  if (BIAS) {
    *(float4*)&bb2[0] = *(const float4*)(bias + n0 + tx * 8);
    *(float4*)&bb2[4] = *(const float4*)(bias + n0 + tx * 8 + 4);
  }
#pragma unroll
  for (int i = 0; i < 8; ++i) {
    float o[8];
#pragma unroll
    for (int j = 0; j < 8; ++j) {
      float v = c[i][j];
      if (BIAS) v += bb2[j];
      if (RELU) v = fmaxf(v, 0.f);
      o[j] = v;
    }
    size_t off = (size_t)(m0 + ty * 8 + i) * N + n0 + tx * 8;
    *(float4*)&C[off]     = make_float4(o[0], o[1], o[2], o[3]);
    *(float4*)&C[off + 4] = make_float4(o[4], o[5], o[6], o[7]);
  }
}

// ---------------- bf16 MFMA flash attention ----------------
// Per block: one (b,h), 128 q rows; 4 waves x 32 q each. KV tile = 64 keys, double-buffered.
// S^T = mfma(K_frag, Q_frag) -> stats lane-local (q = lane&31).
// O^T = mfma(Vt_frag, P_frag) -> rescale/divide lane-uniform.
__global__ __launch_bounds__(256) void attn_mfma(const u16* __restrict__ qb,
                                                 const u16* __restrict__ kb,
                                                 const u16* __restrict__ vtb,
                                                 float* __restrict__ outb) {
  const int logical = ((blockIdx.x & 7) << 5) | (blockIdx.x >> 3);  // XCD swizzle (256%8==0)
  const int bh = logical >> 4;
  const int qt = logical & 15;
  const int t = threadIdx.x;
  const int w = t >> 6, lane = t & 63;
  const int l31 = lane & 31, hi = lane >> 5;

  __shared__ u16 Kf[2][4096];  // frag-linear: frag f=(ktile*4+c), (f*64+lane)*8 shorts
  __shared__ u16 Vf[2][4096];

  const size_t bh_off = (size_t)bh << 17;  // bh * 2048 * 64
  const int q0 = (qt << 7) + (w << 5);

  // Q fragments (B-operand): qa[c] = Q[q0+l31][c*16 + hi*8 .. +7]
  s16x8 qa[4];
  {
    const u16* qrow = qb + bh_off + (size_t)(q0 + l31) * 64 + hi * 8;
#pragma unroll
    for (int c = 0; c < 4; ++c) { B128 tmp; tmp.q = *(const uint4*)(qrow + c * 16); qa[c] = tmp.v; }
  }

  f32x16v ot0, ot1;
#pragma unroll
  for (int i = 0; i < 16; ++i) { ot0[i] = 0.f; ot1[i] = 0.f; }
  float mreg = -3e38f, lreg = 0.f;

  // staging: thread t handles tile row srow, cols scol..scol+15; two 16B chunks -> frag-linear
  const int srow = t >> 2, scol = (t & 3) << 4;
  const int wb0 = (((((srow >> 5) << 2) + (t & 3)) << 6) + (srow & 31)) << 3;  // shorts
  const u16* ksrc = kb + bh_off + (size_t)srow * 64 + scol;    // K[key][dk], +jt*4096
  const u16* vsrc = vtb + bh_off + (size_t)srow * 2048 + scol; // Vt[dk][key], +jt*64

  {  // prologue: stage tile 0 into buf 0
    uint4 k0 = *(const uint4*)ksrc, k1 = *(const uint4*)(ksrc + 8);
    uint4 v0 = *(const uint4*)vsrc, v1 = *(const uint4*)(vsrc + 8);
    *(uint4*)&Kf[0][wb0] = k0; *(uint4*)&Kf[0][wb0 + 256] = k1;
    *(uint4*)&Vf[0][wb0] = v0; *(uint4*)&Vf[0][wb0 + 256] = v1;
  }
  __syncthreads();

  for (int jt = 0; jt < 32; ++jt) {
    const int cur = jt & 1;
    uint4 k0, k1, v0, v1;
    const bool more = (jt < 31);
    if (more) {  // issue next-tile global loads early (latency hides under compute)
      const u16* kp = ksrc + (size_t)(jt + 1) * 4096;
      const u16* vp = vsrc + (size_t)(jt + 1) * 64;
      k0 = *(const uint4*)kp; k1 = *(const uint4*)(kp + 8);
      v0 = *(const uint4*)vp; v1 = *(const uint4*)(vp + 8);
    }

    // QK^T (transposed): st[kt] rows = keys, cols = q
    f32x16v st0, st1;
#pragma unroll
    for (int i = 0; i < 16; ++i) { st0[i] = 0.f; st1[i] = 0.f; }
#pragma unroll
    for (int c = 0; c < 4; ++c) {
      B128 kf0, kf1;
      kf0.q = *(const uint4*)&Kf[cur][(c * 64 + lane) * 8];
      kf1.q = *(const uint4*)&Kf[cur][((c + 4) * 64 + lane) * 8];
      st0 = __builtin_amdgcn_mfma_f32_32x32x16_bf16(kf0.v, qa[c], st0, 0, 0, 0);
      st1 = __builtin_amdgcn_mfma_f32_32x32x16_bf16(kf1.v, qa[c], st1, 0, 0, 0);
    }

    // online softmax: all stats for q = l31 live in lanes {lane, lane^32}
    float mx = -3e38f;
#pragma unroll
    for (int i = 0; i < 16; ++i) { mx = fmaxf(mx, st0[i]); mx = fmaxf(mx, st1[i]); }
    mx = fmaxf(mx, __shfl_xor(mx, 32));
    const float mnew = fmaxf(mreg, mx);
    const float sc = __expf(mreg - mnew);
    mreg = mnew;
    float pv[32];
    float ps = 0.f;
#pragma unroll
    for (int i = 0; i < 16; ++i) { pv[i] = __expf(st0[i] - mnew); ps += pv[i]; }
#pragma unroll
    for (int i = 0; i < 16; ++i) { pv[16 + i] = __expf(st1[i] - mnew); ps += pv[16 + i]; }
    ps += __shfl_xor(ps, 32);
    lreg = lreg * sc + ps;
    ot0 *= sc; ot1 *= sc;

    // pack P -> bf16 dword pairs qp[kt][R]; reg r=4R+rr holds key_in_tile = 8R+rr+4*hi
    u32 qp[2][4][2];
#pragma unroll
    for (int kt = 0; kt < 2; ++kt)
#pragma unroll
      for (int R = 0; R < 4; ++R) {
        qp[kt][R][0] = pk2trunc(pv[kt * 16 + R * 4 + 0], pv[kt * 16 + R * 4 + 1]);
        qp[kt][R][1] = pk2trunc(pv[kt * 16 + R * 4 + 2], pv[kt * 16 + R * 4 + 3]);
      }
    // build PV B-operand fragments pa[c]: needs keys c*16 + hi*8 + j; half-exchange via shfl_xor(32)
    s16x8 pa[4];
#pragma unroll
    for (int kt = 0; kt < 2; ++kt)
#pragma unroll
      for (int cc = 0; cc < 2; ++cc) {
        const u32 a0 = qp[kt][2 * cc][0], a1 = qp[kt][2 * cc][1];
        const u32 b0 = qp[kt][2 * cc + 1][0], b1 = qp[kt][2 * cc + 1][1];
        const u32 xa0 = __shfl_xor(a0, 32), xa1 = __shfl_xor(a1, 32);
        const u32 xb0 = __shfl_xor(b0, 32), xb1 = __shfl_xor(b1, 32);
        B128 f;
        if (hi == 0) { f.u[0] = a0;  f.u[1] = a1;  f.u[2] = xa0; f.u[3] = xa1; }
        else         { f.u[0] = xb0; f.u[1] = xb1; f.u[2] = b0;  f.u[3] = b1;  }
        pa[kt * 2 + cc] = f.v;
      }

    // PV: O^T[v][q] += Vt_frag x P
#pragma unroll
    for (int c = 0; c < 4; ++c) {
      B128 vf0, vf1;
      vf0.q = *(const uint4*)&Vf[cur][(c * 64 + lane) * 8];
      vf1.q = *(const uint4*)&Vf[cur][((c + 4) * 64 + lane) * 8];
      ot0 = __builtin_amdgcn_mfma_f32_32x32x16_bf16(vf0.v, pa[c], ot0, 0, 0, 0);
      ot1 = __builtin_amdgcn_mfma_f32_32x32x16_bf16(vf1.v, pa[c], ot1, 0, 0, 0);
    }

    if (more) {  // write next tile into other buffer (read at jt+1; prior reads fenced by last barrier)
      const int nb = cur ^ 1;
      *(uint4*)&Kf[nb][wb0] = k0; *(uint4*)&Kf[nb][wb0 + 256] = k1;
      *(uint4*)&Vf[nb][wb0] = v0; *(uint4*)&Vf[nb][wb0 + 256] = v1;
    }
    __syncthreads();
  }

  // epilogue: O[q][v]: q = l31 (lane-uniform stats), v = vt*32 + (r&3)+8*(r>>2)+4*hi
  const float linv = 1.f / lreg;
  float* orow = outb + ((size_t)(bh >> 3) * CL + q0 + l31) * CD + (bh & 7) * 64;
#pragma unroll
  for (int R = 0; R < 4; ++R) {
    float4 o0 = make_float4(ot0[4 * R] * linv, ot0[4 * R + 1] * linv,
                            ot0[4 * R + 2] * linv, ot0[4 * R + 3] * linv);
    float4 o1 = make_float4(ot1[4 * R] * linv, ot1[4 * R + 1] * linv,
                            ot1[4 * R + 2] * linv, ot1[4 * R + 3] * linv);
    *(float4*)(orow + R * 8 + hi * 4) = o0;
    *(float4*)(orow + 32 + R * 8 + hi * 4) = o1;
  }
}

// ---------------- fused residual add + LayerNorm (ddof=1, /(sigma+eps)) ----------------
__global__ __launch_bounds__(256) void add_ln(const float* __restrict__ u,
                                              const float* __restrict__ v,
                                              const float* __restrict__ ga,
                                              const float* __restrict__ gb,
                                              float* __restrict__ out) {
  const int row  = blockIdx.x * 4 + (threadIdx.x >> 6);
  const int lane = threadIdx.x & 63;
  const size_t base = (size_t)row * CD;
  float4 u0 = *(const float4*)(u + base + lane * 4);
  float4 v0 = *(const float4*)(v + base + lane * 4);
  float4 u1 = *(const float4*)(u + base + 256 + lane * 4);
  float4 v1 = *(const float4*)(v + base + 256 + lane * 4);
  float z[8] = { u0.x + v0.x, u0.y + v0.y, u0.z + v0.z, u0.w + v0.w,
                 u1.x + v1.x, u1.y + v1.y, u1.z + v1.z, u1.w + v1.w };
  float sum = 0.f, sq = 0.f;
#pragma unroll
  for (int i = 0; i < 8; ++i) { sum += z[i]; sq = fmaf(z[i], z[i], sq); }
#pragma unroll
  for (int off = 32; off > 0; off >>= 1) {
    sum += __shfl_xor(sum, off);
    sq  += __shfl_xor(sq, off);
  }
  float mean = sum * (1.f / CD);
  float var  = fmaxf((sq - (float)CD * mean * mean) * (1.f / (CD - 1)), 0.f);
  float inv  = 1.f / (sqrtf(var) + CEPS);
  float4 a0 = *(const float4*)(ga + lane * 4);
  float4 a1 = *(const float4*)(ga + 256 + lane * 4);
  float4 b0 = *(const float4*)(gb + lane * 4);
  float4 b1 = *(const float4*)(gb + 256 + lane * 4);
  float4 y0 = make_float4(fmaf((z[0] - mean) * inv, a0.x, b0.x),
                          fmaf((z[1] - mean) * inv, a0.y, b0.y),
                          fmaf((z[2] - mean) * inv, a0.z, b0.z),
                          fmaf((z[3] - mean) * inv, a0.w, b0.w));
  float4 y1 = make_float4(fmaf((z[4] - mean) * inv, a1.x, b1.x),
                          fmaf((z[5] - mean) * inv, a1.y, b1.y),
                          fmaf((z[6] - mean) * inv, a1.z, b1.z),
                          fmaf((z[7] - mean) * inv, a1.w, b1.w));
  *(float4*)(out + base + lane * 4)       = y0;
  *(float4*)(out + base + 256 + lane * 4) = y1;
}

extern "C" void kernel_launch(void* const* d_in, const int* in_sizes, int n_in,
                              void* d_out, int out_size, void* d_ws, size_t ws_size,
                              hipStream_t stream) {
  (void)in_sizes; (void)n_in; (void)out_size; (void)ws_size;
  const float* x    = (const float*)d_in[0];
  const float* pos  = (const float*)d_in[1];
  const float* wq   = (const float*)d_in[2];
  const float* wk   = (const float*)d_in[3];
  const float* wv   = (const float*)d_in[4];
  const float* ln1a = (const float*)d_in[5];
  const float* ln1b = (const float*)d_in[6];
  const float* w1   = (const float*)d_in[7];
  const float* b1   = (const float*)d_in[8];
  const float* w2   = (const float*)d_in[9];
  const float* b2   = (const float*)d_in[10];
  const float* ln2a = (const float*)d_in[11];
  const float* ln2b = (const float*)d_in[12];

  float* ws = (float*)d_ws;
  float* xw   = ws;                    // 2M floats
  float* x1   = xw + 2097152;          // 2M
  float* wqkv = x1 + 2097152;          // 1.5M
  float* ff1  = wqkv + 1572864;        // 4M  (attb overlays: attb dead before ff1 written)
  float* ff2  = ff1 + 4194304;         // 2M  (qbuf+kbuf overlay: dead before ff2 written)
  float* vt_f = ff2 + 2097152;         // 1M floats = 2M shorts
  float* attb = ff1;
  u16* qbuf  = (u16*)ff2;              // 2M shorts
  u16* kbuf  = qbuf + 2097152;         // 2M shorts
  u16* vtbuf = (u16*)vt_f;             // 2M shorts

  repack_qkv<<<6144, 256, 0, stream>>>(wq, wk, wv, wqkv);
  add_pos<<<2048, 256, 0, stream>>>((const float4*)x, (const float4*)pos, (float4*)xw);

  for (int l = 0; l < CNL; ++l) {
    gemm_f32<1, false, false><<<dim3(12, 32), 256, 0, stream>>>(
        xw, wqkv + (size_t)l * 1536 * CD, nullptr, nullptr, qbuf, kbuf, vtbuf, 4096, 1536, 512);
    attn_mfma<<<256, 256, 0, stream>>>(qbuf, kbuf, vtbuf, attb);
    add_ln<<<1024, 256, 0, stream>>>(attb, xw, ln1a + l * CD, ln1b + l * CD, x1);
    gemm_f32<0, true, true><<<dim3(8, 32), 256, 0, stream>>>(
        x1, w1 + (size_t)l * CDFF * CD, b1 + l * CDFF, ff1, nullptr, nullptr, nullptr, 4096, 1024, 512);
    gemm_f32<0, true, false><<<dim3(4, 32), 256, 0, stream>>>(
        ff1, w2 + (size_t)l * CD * CDFF, b2 + l * CD, ff2, nullptr, nullptr, nullptr, 4096, 512, 1024);
    float* dst = (l == CNL - 1) ? (float*)d_out : xw;
    add_ln<<<1024, 256, 0, stream>>>(ff2, x1, ln2a + l * CD, ln2b + l * CD, dst);
  }
}

// Round 4
// 450.472 us; speedup vs baseline: 4.9169x; 1.8102x over previous
//
#include <hip/hip_runtime.h>
#include <cstddef>
#include <cstdint>

typedef unsigned int u32;
typedef unsigned short u16;

constexpr int CB = 2, CL = 2048, CD = 512, CH = 8, CNL = 2, CDFF = 1024;
constexpr float CEPS = 1e-3f;
constexpr float INV_TEMPER = 0.044194173824159216f;  // 1/sqrt(512)

typedef __attribute__((ext_vector_type(16))) float f32x16v;
typedef __attribute__((ext_vector_type(8))) short s16x8;

union B128 { s16x8 v; uint4 q; u32 u[4]; };

__device__ inline u16 f2bf(float f) {
  union { float f; u32 u; } x; x.f = f;
  u32 r = x.u + 0x7fffu + ((x.u >> 16) & 1u);
  return (u16)(r >> 16);
}
__device__ inline u32 pk2rne(float a, float b) {
  return (u32)f2bf(a) | ((u32)f2bf(b) << 16);
}
__device__ inline u32 pk2trunc(float a, float b) {  // P in [0,1]: truncation ok
  union { float f; u32 u; } xa, xb; xa.f = a; xb.f = b;
  return (xa.u >> 16) | (xb.u & 0xffff0000u);
}

// ---- repack wq/wk/wv (NL,H,D,DK) f32 -> (NL, 1536, D) bf16 (N,K); wq pre-scaled by 1/temper ----
__global__ __launch_bounds__(256) void repack_qkv(const float* __restrict__ wq,
                                                  const float* __restrict__ wk,
                                                  const float* __restrict__ wv,
                                                  u16* __restrict__ dst) {
  int i = blockIdx.x * 256 + threadIdx.x;
  int d = i & (CD - 1);
  int rest = i >> 9;
  int n = rest % 1536;
  int l = rest / 1536;
  int which = n >> 9;
  int r = n & 511;
  int hh = r >> 6;
  int kk = r & 63;
  const float* src = (which == 0) ? wq : (which == 1) ? wk : wv;
  float v = src[(((size_t)l * CH + hh) * CD + d) * 64 + kk];
  if (which == 0) v *= INV_TEMPER;
  dst[i] = f2bf(v);
}

// ---- f32 -> bf16 cast (float4 per thread) ----
__global__ __launch_bounds__(256) void cast_bf16(const float4* __restrict__ in,
                                                 uint2* __restrict__ out) {
  int i = blockIdx.x * 256 + threadIdx.x;
  float4 v = in[i];
  uint2 p; p.x = pk2rne(v.x, v.y); p.y = pk2rne(v.z, v.w);
  out[i] = p;
}

// ---- x + pos -> f32 xw and bf16 xb ----
__global__ __launch_bounds__(256) void add_pos(const float4* __restrict__ x,
                                               const float4* __restrict__ pos,
                                               float4* __restrict__ out,
                                               uint2* __restrict__ outb) {
  int i = blockIdx.x * 256 + threadIdx.x;
  float4 a = x[i];
  float4 p = pos[i & (CL * CD / 4 - 1)];
  float4 r = make_float4(a.x + p.x, a.y + p.y, a.z + p.z, a.w + p.w);
  out[i] = r;
  uint2 pk; pk.x = pk2rne(r.x, r.y); pk.y = pk2rne(r.z, r.w);
  outb[i] = pk;
}

// ---------------- bf16 MFMA GEMM: C[M,N] = A[M,K] * W[N,K]^T ----------------
// MODE 0: f32 out + bias. MODE 1: bf16 out + bias + relu. MODE 2: QKV epilogue.
// BN = 64*BNT. Block 256 thr = 4 waves (2x2), wave tile 64 x 32*BNT. BK=64, double-buffered.
// Frag-linear LDS (identical lane mapping to the proven attn kernel): conflict-free.
template<int MODE, int BNT>
__global__ __launch_bounds__(256) void gemm_bf16(const u16* __restrict__ A,
                                                 const u16* __restrict__ W,
                                                 const float* __restrict__ bias,
                                                 float* __restrict__ Cf,
                                                 u16* __restrict__ Cb,
                                                 u16* __restrict__ kbuf,
                                                 u16* __restrict__ vtbuf,
                                                 int M, int N, int K) {
  __shared__ u16 Asm[2][8192];
  __shared__ u16 Wsm[2][BNT * 4096];
  const int t = threadIdx.x;
  const int w = t >> 6, lane = t & 63;
  const int wr = w >> 1, wc = w & 1;
  const int l31 = lane & 31, hi = lane >> 5;
  const int m0 = blockIdx.y * 128, n0 = blockIdx.x * (64 * BNT);

  const int srow = t >> 3;          // 0..31
  const int scol = (t & 7) * 8;     // 0,8,..,56
  const u16* aglo = A + (size_t)(m0 + srow) * K + scol;
  const u16* wglo = W + (size_t)(n0 + srow) * K + scol;
  // frag-linear dst: ((rg*4 + ks)*64 + lane')*8 ; rg = i, ks = (t&7)>>1, lane' = srow + 32*((t&7)&1)
  const int dbase = ((((t & 7) >> 1) * 64) + srow + ((t & 7) & 1) * 32) * 8;

  {  // prologue: stage k-tile 0 into buf 0
#pragma unroll
    for (int i = 0; i < 4; ++i)
      *(uint4*)&Asm[0][dbase + i * 2048] = *(const uint4*)(aglo + (size_t)(32 * i) * K);
#pragma unroll
    for (int i = 0; i < 2 * BNT; ++i)
      *(uint4*)&Wsm[0][dbase + i * 2048] = *(const uint4*)(wglo + (size_t)(32 * i) * K);
  }
  __syncthreads();

  f32x16v acc[2][BNT];
#pragma unroll
  for (int mt = 0; mt < 2; ++mt)
#pragma unroll
    for (int nt = 0; nt < BNT; ++nt)
#pragma unroll
      for (int i = 0; i < 16; ++i) acc[mt][nt][i] = 0.f;

  const int nk = K >> 6;
  for (int kb = 0; kb < nk; ++kb) {
    const int cur = kb & 1;
    uint4 an[4], wn[2 * BNT];
    const bool more = (kb + 1 < nk);
    if (more) {  // issue next-tile global loads early
      const u16* ap = aglo + (kb + 1) * 64;
      const u16* wp = wglo + (kb + 1) * 64;
#pragma unroll
      for (int i = 0; i < 4; ++i) an[i] = *(const uint4*)(ap + (size_t)(32 * i) * K);
#pragma unroll
      for (int i = 0; i < 2 * BNT; ++i) wn[i] = *(const uint4*)(wp + (size_t)(32 * i) * K);
    }
    __builtin_amdgcn_s_setprio(1);
#pragma unroll
    for (int ks = 0; ks < 4; ++ks) {
      B128 af[2], bf[BNT];
#pragma unroll
      for (int mt = 0; mt < 2; ++mt)
        af[mt].q = *(const uint4*)&Asm[cur][(((wr * 2 + mt) * 4 + ks) * 64 + lane) * 8];
#pragma unroll
      for (int nt = 0; nt < BNT; ++nt)
        bf[nt].q = *(const uint4*)&Wsm[cur][(((wc * BNT + nt) * 4 + ks) * 64 + lane) * 8];
#pragma unroll
      for (int mt = 0; mt < 2; ++mt)
#pragma unroll
        for (int nt = 0; nt < BNT; ++nt)
          acc[mt][nt] = __builtin_amdgcn_mfma_f32_32x32x16_bf16(af[mt].v, bf[nt].v, acc[mt][nt], 0, 0, 0);
    }
    __builtin_amdgcn_s_setprio(0);
    if (more) {
      const int nb = cur ^ 1;
#pragma unroll
      for (int i = 0; i < 4; ++i) *(uint4*)&Asm[nb][dbase + i * 2048] = an[i];
#pragma unroll
      for (int i = 0; i < 2 * BNT; ++i) *(uint4*)&Wsm[nb][dbase + i * 2048] = wn[i];
    }
    __syncthreads();
  }

  if (MODE == 2) {
    // N=1536: region uniform per block (BN=128 divides 512 boundaries)
    const int region = n0 >> 9;
    const int bidx = m0 >> 11;
    const int lb0 = (m0 & 2047) + wr * 64;
#pragma unroll
    for (int nt = 0; nt < BNT; ++nt) {
      const int ncol = wc * 64 + nt * 32;
      const int hh = ((n0 & 511) + ncol) >> 6;
      const int dk = (ncol & 63) + l31;
      const int bh = bidx * 8 + hh;
      if (region <= 1) {
        u16* qk = (region == 0 ? Cb : kbuf) + ((size_t)bh << 17) + dk;
#pragma unroll
        for (int mt = 0; mt < 2; ++mt)
#pragma unroll
          for (int r = 0; r < 16; ++r) {
            const int l = lb0 + mt * 32 + (r & 3) + 8 * (r >> 2) + 4 * hi;
            qk[(size_t)l * 64] = f2bf(acc[mt][nt][r]);
          }
      } else {
        u16* vb = vtbuf + ((size_t)(bh * 64 + dk)) * 2048;
#pragma unroll
        for (int mt = 0; mt < 2; ++mt)
#pragma unroll
          for (int R = 0; R < 4; ++R) {
            const int l = lb0 + mt * 32 + 8 * R + 4 * hi;
            uint2 pk;
            pk.x = pk2rne(acc[mt][nt][4 * R + 0], acc[mt][nt][4 * R + 1]);
            pk.y = pk2rne(acc[mt][nt][4 * R + 2], acc[mt][nt][4 * R + 3]);
            *(uint2*)(vb + l) = pk;
          }
      }
    }
    return;
  }

  const int gmb = m0 + wr * 64;
  const int gnb = n0 + wc * 32 * BNT;
#pragma unroll
  for (int nt = 0; nt < BNT; ++nt) {
    const int gn = gnb + nt * 32 + l31;
    const float bv = bias[gn];
#pragma unroll
    for (int mt = 0; mt < 2; ++mt)
#pragma unroll
      for (int r = 0; r < 16; ++r) {
        const int gm = gmb + mt * 32 + (r & 3) + 8 * (r >> 2) + 4 * hi;
        float v = acc[mt][nt][r] + bv;
        if (MODE == 1) {
          v = fmaxf(v, 0.f);
          Cb[(size_t)gm * N + gn] = f2bf(v);
        } else {
          Cf[(size_t)gm * N + gn] = v;
        }
      }
  }
}

// ---------------- bf16 MFMA flash attention (unchanged structure + setprio) ----------------
__global__ __launch_bounds__(256) void attn_mfma(const u16* __restrict__ qb,
                                                 const u16* __restrict__ kb,
                                                 const u16* __restrict__ vtb,
                                                 float* __restrict__ outb) {
  const int logical = ((blockIdx.x & 7) << 5) | (blockIdx.x >> 3);  // XCD swizzle
  const int bh = logical >> 4;
  const int qt = logical & 15;
  const int t = threadIdx.x;
  const int w = t >> 6, lane = t & 63;
  const int l31 = lane & 31, hi = lane >> 5;

  __shared__ u16 Kf[2][4096];
  __shared__ u16 Vf[2][4096];

  const size_t bh_off = (size_t)bh << 17;
  const int q0 = (qt << 7) + (w << 5);

  s16x8 qa[4];
  {
    const u16* qrow = qb + bh_off + (size_t)(q0 + l31) * 64 + hi * 8;
#pragma unroll
    for (int c = 0; c < 4; ++c) { B128 tmp; tmp.q = *(const uint4*)(qrow + c * 16); qa[c] = tmp.v; }
  }

  f32x16v ot0, ot1;
#pragma unroll
  for (int i = 0; i < 16; ++i) { ot0[i] = 0.f; ot1[i] = 0.f; }
  float mreg = -3e38f, lreg = 0.f;

  const int srow = t >> 2, scol = (t & 3) << 4;
  const int wb0 = (((((srow >> 5) << 2) + (t & 3)) << 6) + (srow & 31)) << 3;
  const u16* ksrc = kb + bh_off + (size_t)srow * 64 + scol;
  const u16* vsrc = vtb + bh_off + (size_t)srow * 2048 + scol;

  {
    uint4 k0 = *(const uint4*)ksrc, k1 = *(const uint4*)(ksrc + 8);
    uint4 v0 = *(const uint4*)vsrc, v1 = *(const uint4*)(vsrc + 8);
    *(uint4*)&Kf[0][wb0] = k0; *(uint4*)&Kf[0][wb0 + 256] = k1;
    *(uint4*)&Vf[0][wb0] = v0; *(uint4*)&Vf[0][wb0 + 256] = v1;
  }
  __syncthreads();

  for (int jt = 0; jt < 32; ++jt) {
    const int cur = jt & 1;
    uint4 k0, k1, v0, v1;
    const bool more = (jt < 31);
    if (more) {
      const u16* kp = ksrc + (size_t)(jt + 1) * 4096;
      const u16* vp = vsrc + (size_t)(jt + 1) * 64;
      k0 = *(const uint4*)kp; k1 = *(const uint4*)(kp + 8);
      v0 = *(const uint4*)vp; v1 = *(const uint4*)(vp + 8);
    }

    f32x16v st0, st1;
#pragma unroll
    for (int i = 0; i < 16; ++i) { st0[i] = 0.f; st1[i] = 0.f; }
    __builtin_amdgcn_s_setprio(1);
#pragma unroll
    for (int c = 0; c < 4; ++c) {
      B128 kf0, kf1;
      kf0.q = *(const uint4*)&Kf[cur][(c * 64 + lane) * 8];
      kf1.q = *(const uint4*)&Kf[cur][((c + 4) * 64 + lane) * 8];
      st0 = __builtin_amdgcn_mfma_f32_32x32x16_bf16(kf0.v, qa[c], st0, 0, 0, 0);
      st1 = __builtin_amdgcn_mfma_f32_32x32x16_bf16(kf1.v, qa[c], st1, 0, 0, 0);
    }
    __builtin_amdgcn_s_setprio(0);

    float mx = -3e38f;
#pragma unroll
    for (int i = 0; i < 16; ++i) { mx = fmaxf(mx, st0[i]); mx = fmaxf(mx, st1[i]); }
    mx = fmaxf(mx, __shfl_xor(mx, 32));
    const float mnew = fmaxf(mreg, mx);
    const float sc = __expf(mreg - mnew);
    mreg = mnew;
    float pv[32];
    float ps = 0.f;
#pragma unroll
    for (int i = 0; i < 16; ++i) { pv[i] = __expf(st0[i] - mnew); ps += pv[i]; }
#pragma unroll
    for (int i = 0; i < 16; ++i) { pv[16 + i] = __expf(st1[i] - mnew); ps += pv[16 + i]; }
    ps += __shfl_xor(ps, 32);
    lreg = lreg * sc + ps;
    ot0 *= sc; ot1 *= sc;

    u32 qp[2][4][2];
#pragma unroll
    for (int kt = 0; kt < 2; ++kt)
#pragma unroll
      for (int R = 0; R < 4; ++R) {
        qp[kt][R][0] = pk2trunc(pv[kt * 16 + R * 4 + 0], pv[kt * 16 + R * 4 + 1]);
        qp[kt][R][1] = pk2trunc(pv[kt * 16 + R * 4 + 2], pv[kt * 16 + R * 4 + 3]);
      }
    s16x8 pa[4];
#pragma unroll
    for (int kt = 0; kt < 2; ++kt)
#pragma unroll
      for (int cc = 0; cc < 2; ++cc) {
        const u32 a0 = qp[kt][2 * cc][0], a1 = qp[kt][2 * cc][1];
        const u32 b0 = qp[kt][2 * cc + 1][0], b1 = qp[kt][2 * cc + 1][1];
        const u32 xa0 = __shfl_xor(a0, 32), xa1 = __shfl_xor(a1, 32);
        const u32 xb0 = __shfl_xor(b0, 32), xb1 = __shfl_xor(b1, 32);
        B128 f;
        if (hi == 0) { f.u[0] = a0;  f.u[1] = a1;  f.u[2] = xa0; f.u[3] = xa1; }
        else         { f.u[0] = xb0; f.u[1] = xb1; f.u[2] = b0;  f.u[3] = b1;  }
        pa[kt * 2 + cc] = f.v;
      }

    __builtin_amdgcn_s_setprio(1);
#pragma unroll
    for (int c = 0; c < 4; ++c) {
      B128 vf0, vf1;
      vf0.q = *(const uint4*)&Vf[cur][(c * 64 + lane) * 8];
      vf1.q = *(const uint4*)&Vf[cur][((c + 4) * 64 + lane) * 8];
      ot0 = __builtin_amdgcn_mfma_f32_32x32x16_bf16(vf0.v, pa[c], ot0, 0, 0, 0);
      ot1 = __builtin_amdgcn_mfma_f32_32x32x16_bf16(vf1.v, pa[c], ot1, 0, 0, 0);
    }
    __builtin_amdgcn_s_setprio(0);

    if (more) {
      const int nb = cur ^ 1;
      *(uint4*)&Kf[nb][wb0] = k0; *(uint4*)&Kf[nb][wb0 + 256] = k1;
      *(uint4*)&Vf[nb][wb0] = v0; *(uint4*)&Vf[nb][wb0 + 256] = v1;
    }
    __syncthreads();
  }

  const float linv = 1.f / lreg;
  float* orow = outb + ((size_t)(bh >> 3) * CL + q0 + l31) * CD + (bh & 7) * 64;
#pragma unroll
  for (int R = 0; R < 4; ++R) {
    float4 o0 = make_float4(ot0[4 * R] * linv, ot0[4 * R + 1] * linv,
                            ot0[4 * R + 2] * linv, ot0[4 * R + 3] * linv);
    float4 o1 = make_float4(ot1[4 * R] * linv, ot1[4 * R + 1] * linv,
                            ot1[4 * R + 2] * linv, ot1[4 * R + 3] * linv);
    *(float4*)(orow + R * 8 + hi * 4) = o0;
    *(float4*)(orow + 32 + R * 8 + hi * 4) = o1;
  }
}

// ---------------- fused residual add + LayerNorm; optional bf16 copy out ----------------
__global__ __launch_bounds__(256) void add_ln(const float* __restrict__ u,
                                              const float* __restrict__ v,
                                              const float* __restrict__ ga,
                                              const float* __restrict__ gb,
                                              float* __restrict__ out,
                                              u16* __restrict__ bfout) {
  const int row  = blockIdx.x * 4 + (threadIdx.x >> 6);
  const int lane = threadIdx.x & 63;
  const size_t base = (size_t)row * CD;
  float4 u0 = *(const float4*)(u + base + lane * 4);
  float4 v0 = *(const float4*)(v + base + lane * 4);
  float4 u1 = *(const float4*)(u + base + 256 + lane * 4);
  float4 v1 = *(const float4*)(v + base + 256 + lane * 4);
  float z[8] = { u0.x + v0.x, u0.y + v0.y, u0.z + v0.z, u0.w + v0.w,
                 u1.x + v1.x, u1.y + v1.y, u1.z + v1.z, u1.w + v1.w };
  float sum = 0.f, sq = 0.f;
#pragma unroll
  for (int i = 0; i < 8; ++i) { sum += z[i]; sq = fmaf(z[i], z[i], sq); }
#pragma unroll
  for (int off = 32; off > 0; off >>= 1) {
    sum += __shfl_xor(sum, off);
    sq  += __shfl_xor(sq, off);
  }
  float mean = sum * (1.f / CD);
  float var  = fmaxf((sq - (float)CD * mean * mean) * (1.f / (CD - 1)), 0.f);
  float inv  = 1.f / (sqrtf(var) + CEPS);
  float4 a0 = *(const float4*)(ga + lane * 4);
  float4 a1 = *(const float4*)(ga + 256 + lane * 4);
  float4 b0 = *(const float4*)(gb + lane * 4);
  float4 b1 = *(const float4*)(gb + 256 + lane * 4);
  float4 y0 = make_float4(fmaf((z[0] - mean) * inv, a0.x, b0.x),
                          fmaf((z[1] - mean) * inv, a0.y, b0.y),
                          fmaf((z[2] - mean) * inv, a0.z, b0.z),
                          fmaf((z[3] - mean) * inv, a0.w, b0.w));
  float4 y1 = make_float4(fmaf((z[4] - mean) * inv, a1.x, b1.x),
                          fmaf((z[5] - mean) * inv, a1.y, b1.y),
                          fmaf((z[6] - mean) * inv, a1.z, b1.z),
                          fmaf((z[7] - mean) * inv, a1.w, b1.w));
  *(float4*)(out + base + lane * 4)       = y0;
  *(float4*)(out + base + 256 + lane * 4) = y1;
  if (bfout) {
    uint2 p0; p0.x = pk2rne(y0.x, y0.y); p0.y = pk2rne(y0.z, y0.w);
    uint2 p1; p1.x = pk2rne(y1.x, y1.y); p1.y = pk2rne(y1.z, y1.w);
    *(uint2*)(bfout + base + lane * 4)       = p0;
    *(uint2*)(bfout + base + 256 + lane * 4) = p1;
  }
}

extern "C" void kernel_launch(void* const* d_in, const int* in_sizes, int n_in,
                              void* d_out, int out_size, void* d_ws, size_t ws_size,
                              hipStream_t stream) {
  (void)in_sizes; (void)n_in; (void)out_size; (void)ws_size;
  const float* x    = (const float*)d_in[0];
  const float* pos  = (const float*)d_in[1];
  const float* wq   = (const float*)d_in[2];
  const float* wk   = (const float*)d_in[3];
  const float* wv   = (const float*)d_in[4];
  const float* ln1a = (const float*)d_in[5];
  const float* ln1b = (const float*)d_in[6];
  const float* w1   = (const float*)d_in[7];
  const float* b1   = (const float*)d_in[8];
  const float* w2   = (const float*)d_in[9];
  const float* b2   = (const float*)d_in[10];
  const float* ln2a = (const float*)d_in[11];
  const float* ln2b = (const float*)d_in[12];

  float* ws = (float*)d_ws;
  float* xw  = ws;                    // 2M f32: residual stream
  float* x1  = xw + 2097152;          // 2M f32: LN1 out
  float* rA  = x1 + 2097152;          // 2M f32: attb (f32) | ff1b (4M u16)
  float* rB  = rA + 2097152;          // 2M f32: ff2 (f32) | qbuf+kbuf (4M u16)
  float* rC  = rB + 2097152;          // 1M f32: vtbuf (2M u16) | x1b (2M u16)
  float* rXb = rC + 1048576;          // 1M f32: xb (2M u16)
  float* rWq = rXb + 1048576;         // 786432 f32: wqkvb (1.57M u16)
  float* rW1 = rWq + 786432;          // 524288 f32: w1b (1.05M u16)
  float* rW2 = rW1 + 524288;          // 524288 f32: w2b  (total 49.3 MB)

  float* attb = rA;
  u16* ff1b  = (u16*)rA;
  float* ff2 = rB;
  u16* qbuf  = (u16*)rB;
  u16* kbuf  = qbuf + 2097152;
  u16* vtbuf = (u16*)rC;
  u16* x1b   = (u16*)rC;
  u16* xb    = (u16*)rXb;
  u16* wqkvb = (u16*)rWq;
  u16* w1b   = (u16*)rW1;
  u16* w2b   = (u16*)rW2;

  repack_qkv<<<6144, 256, 0, stream>>>(wq, wk, wv, wqkvb);
  cast_bf16<<<1024, 256, 0, stream>>>((const float4*)w1, (uint2*)w1b);  // 2*1024*512/4
  cast_bf16<<<1024, 256, 0, stream>>>((const float4*)w2, (uint2*)w2b);
  add_pos<<<2048, 256, 0, stream>>>((const float4*)x, (const float4*)pos,
                                    (float4*)xw, (uint2*)xb);

  for (int l = 0; l < CNL; ++l) {
    gemm_bf16<2, 2><<<dim3(12, 32), 256, 0, stream>>>(
        xb, wqkvb + (size_t)l * 786432, nullptr, nullptr, qbuf, kbuf, vtbuf,
        4096, 1536, 512);
    attn_mfma<<<256, 256, 0, stream>>>(qbuf, kbuf, vtbuf, attb);
    add_ln<<<1024, 256, 0, stream>>>(attb, xw, ln1a + l * CD, ln1b + l * CD, x1, x1b);
    gemm_bf16<1, 2><<<dim3(8, 32), 256, 0, stream>>>(
        x1b, w1b + (size_t)l * 524288, b1 + l * CDFF, nullptr, ff1b, nullptr, nullptr,
        4096, 1024, 512);
    gemm_bf16<0, 1><<<dim3(8, 32), 256, 0, stream>>>(
        ff1b, w2b + (size_t)l * 524288, b2 + l * CD, ff2, nullptr, nullptr, nullptr,
        4096, 512, 1024);
    float* dst = (l == CNL - 1) ? (float*)d_out : xw;
    u16* bdst = (l == CNL - 1) ? nullptr : xb;
    add_ln<<<1024, 256, 0, stream>>>(ff2, x1, ln2a + l * CD, ln2b + l * CD, dst, bdst);
  }
}

// Round 5
// 432.828 us; speedup vs baseline: 5.1174x; 1.0408x over previous
//
#include <hip/hip_runtime.h>
#include <cstddef>
#include <cstdint>

typedef unsigned int u32;
typedef unsigned short u16;

constexpr int CB = 2, CL = 2048, CD = 512, CH = 8, CNL = 2, CDFF = 1024;
constexpr float CEPS = 1e-3f;
constexpr float INV_TEMPER = 0.044194173824159216f;   // 1/sqrt(512)
constexpr float QSCALE = INV_TEMPER * 1.4426950408889634f;  // fold log2e -> exp2 softmax
constexpr float DEFER_THR = 11.0f;                    // log2 units: p <= 2^11

typedef __attribute__((ext_vector_type(16))) float f32x16v;
typedef __attribute__((ext_vector_type(8))) short s16x8;

union B128 { s16x8 v; uint4 q; u32 u[4]; };

__device__ inline u16 f2bf(float f) {
  union { float f; u32 u; } x; x.f = f;
  u32 r = x.u + 0x7fffu + ((x.u >> 16) & 1u);
  return (u16)(r >> 16);
}
__device__ inline u32 pk2rne(float a, float b) {
  return (u32)f2bf(a) | ((u32)f2bf(b) << 16);
}
__device__ inline u32 pk2trunc(float a, float b) {
  union { float f; u32 u; } xa, xb; xa.f = a; xb.f = b;
  return (xa.u >> 16) | (xb.u & 0xffff0000u);
}
__device__ inline float bflo(u32 u) { union { u32 u; float f; } x; x.u = u << 16; return x.f; }
__device__ inline float bfhi(u32 u) { union { u32 u; float f; } x; x.u = u & 0xffff0000u; return x.f; }

// ---- repack wq/wk/wv (NL,H,D,DK) f32 -> (NL, 1536, D) bf16 (N,K); wq pre-scaled by QSCALE ----
__global__ __launch_bounds__(256) void repack_qkv(const float* __restrict__ wq,
                                                  const float* __restrict__ wk,
                                                  const float* __restrict__ wv,
                                                  u16* __restrict__ dst) {
  int i = blockIdx.x * 256 + threadIdx.x;
  int d = i & (CD - 1);
  int rest = i >> 9;
  int n = rest % 1536;
  int l = rest / 1536;
  int which = n >> 9;
  int r = n & 511;
  int hh = r >> 6;
  int kk = r & 63;
  const float* src = (which == 0) ? wq : (which == 1) ? wk : wv;
  float v = src[(((size_t)l * CH + hh) * CD + d) * 64 + kk];
  if (which == 0) v *= QSCALE;
  dst[i] = f2bf(v);
}

__global__ __launch_bounds__(256) void cast_bf16(const float4* __restrict__ in,
                                                 uint2* __restrict__ out) {
  int i = blockIdx.x * 256 + threadIdx.x;
  float4 v = in[i];
  uint2 p; p.x = pk2rne(v.x, v.y); p.y = pk2rne(v.z, v.w);
  out[i] = p;
}

__global__ __launch_bounds__(256) void add_pos(const float4* __restrict__ x,
                                               const float4* __restrict__ pos,
                                               float4* __restrict__ out,
                                               uint2* __restrict__ outb) {
  int i = blockIdx.x * 256 + threadIdx.x;
  float4 a = x[i];
  float4 p = pos[i & (CL * CD / 4 - 1)];
  float4 r = make_float4(a.x + p.x, a.y + p.y, a.z + p.z, a.w + p.w);
  out[i] = r;
  uint2 pk; pk.x = pk2rne(r.x, r.y); pk.y = pk2rne(r.z, r.w);
  outb[i] = pk;
}

// ---------------- bf16 MFMA GEMM: C[M,N] = A[M,K] * W[N,K]^T ----------------
// MODE 0: f32 out + bias. MODE 1: bf16 out + bias + relu. MODE 2: QKV epilogue.
// BM = 64*MT, BN = 64*BNT. 4 waves (2 m x 2 n); wave tile (32*MT) x (32*BNT). BK=64, dbuf.
template<int MODE, int BNT, int MT>
__global__ __launch_bounds__(256) void gemm_bf16(const u16* __restrict__ A,
                                                 const u16* __restrict__ W,
                                                 const float* __restrict__ bias,
                                                 float* __restrict__ Cf,
                                                 u16* __restrict__ Cb,
                                                 u16* __restrict__ kbuf,
                                                 u16* __restrict__ vtbuf,
                                                 int M, int N, int K) {
  __shared__ u16 Asm[2][MT * 4096];
  __shared__ u16 Wsm[2][BNT * 4096];
  const int t = threadIdx.x;
  const int w = t >> 6, lane = t & 63;
  const int wr = w >> 1, wc = w & 1;
  const int l31 = lane & 31, hi = lane >> 5;
  const int m0 = blockIdx.y * (64 * MT), n0 = blockIdx.x * (64 * BNT);

  const int srow = t >> 3;          // 0..31
  const int scol = (t & 7) * 8;     // 0,8,..,56
  const u16* aglo = A + (size_t)(m0 + srow) * K + scol;
  const u16* wglo = W + (size_t)(n0 + srow) * K + scol;
  const int dbase = ((((t & 7) >> 1) * 64) + srow + ((t & 7) & 1) * 32) * 8;

  {  // prologue: stage k-tile 0 into buf 0
#pragma unroll
    for (int i = 0; i < 2 * MT; ++i)
      *(uint4*)&Asm[0][dbase + i * 2048] = *(const uint4*)(aglo + (size_t)(32 * i) * K);
#pragma unroll
    for (int i = 0; i < 2 * BNT; ++i)
      *(uint4*)&Wsm[0][dbase + i * 2048] = *(const uint4*)(wglo + (size_t)(32 * i) * K);
  }
  __syncthreads();

  f32x16v acc[MT][BNT];
#pragma unroll
  for (int mt = 0; mt < MT; ++mt)
#pragma unroll
    for (int nt = 0; nt < BNT; ++nt)
#pragma unroll
      for (int i = 0; i < 16; ++i) acc[mt][nt][i] = 0.f;

  const int nk = K >> 6;
  for (int kb = 0; kb < nk; ++kb) {
    const int cur = kb & 1;
    uint4 an[2 * MT], wn[2 * BNT];
    const bool more = (kb + 1 < nk);
    if (more) {
      const u16* ap = aglo + (kb + 1) * 64;
      const u16* wp = wglo + (kb + 1) * 64;
#pragma unroll
      for (int i = 0; i < 2 * MT; ++i) an[i] = *(const uint4*)(ap + (size_t)(32 * i) * K);
#pragma unroll
      for (int i = 0; i < 2 * BNT; ++i) wn[i] = *(const uint4*)(wp + (size_t)(32 * i) * K);
    }
    __builtin_amdgcn_s_setprio(1);
#pragma unroll
    for (int ks = 0; ks < 4; ++ks) {
      B128 af[MT], bf[BNT];
#pragma unroll
      for (int mt = 0; mt < MT; ++mt)
        af[mt].q = *(const uint4*)&Asm[cur][(((wr * MT + mt) * 4 + ks) * 64 + lane) * 8];
#pragma unroll
      for (int nt = 0; nt < BNT; ++nt)
        bf[nt].q = *(const uint4*)&Wsm[cur][(((wc * BNT + nt) * 4 + ks) * 64 + lane) * 8];
#pragma unroll
      for (int mt = 0; mt < MT; ++mt)
#pragma unroll
        for (int nt = 0; nt < BNT; ++nt)
          acc[mt][nt] = __builtin_amdgcn_mfma_f32_32x32x16_bf16(af[mt].v, bf[nt].v, acc[mt][nt], 0, 0, 0);
    }
    __builtin_amdgcn_s_setprio(0);
    if (more) {
      const int nb = cur ^ 1;
#pragma unroll
      for (int i = 0; i < 2 * MT; ++i) *(uint4*)&Asm[nb][dbase + i * 2048] = an[i];
#pragma unroll
      for (int i = 0; i < 2 * BNT; ++i) *(uint4*)&Wsm[nb][dbase + i * 2048] = wn[i];
    }
    __syncthreads();
  }

  if (MODE == 2) {
    const int region = n0 >> 9;          // BN=64 divides 512 boundaries: uniform per block
    const int bidx = m0 >> 11;
    const int lb0 = (m0 & 2047) + wr * MT * 32;
#pragma unroll
    for (int nt = 0; nt < BNT; ++nt) {
      const int ncol = (wc * BNT + nt) * 32;
      const int hh = ((n0 & 511) + ncol) >> 6;
      const int dk = (ncol & 63) + l31;
      const int bh = bidx * 8 + hh;
      if (region <= 1) {
        u16* qk = (region == 0 ? Cb : kbuf) + ((size_t)bh << 17) + dk;
#pragma unroll
        for (int mt = 0; mt < MT; ++mt)
#pragma unroll
          for (int r = 0; r < 16; ++r) {
            const int l = lb0 + mt * 32 + (r & 3) + 8 * (r >> 2) + 4 * hi;
            qk[(size_t)l * 64] = f2bf(acc[mt][nt][r]);
          }
      } else {
        u16* vb = vtbuf + ((size_t)(bh * 64 + dk)) * 2048;
#pragma unroll
        for (int mt = 0; mt < MT; ++mt)
#pragma unroll
          for (int R = 0; R < 4; ++R) {
            const int l = lb0 + mt * 32 + 8 * R + 4 * hi;
            uint2 pk;
            pk.x = pk2rne(acc[mt][nt][4 * R + 0], acc[mt][nt][4 * R + 1]);
            pk.y = pk2rne(acc[mt][nt][4 * R + 2], acc[mt][nt][4 * R + 3]);
            *(uint2*)(vb + l) = pk;
          }
      }
    }
    return;
  }

  const int gmb = m0 + wr * MT * 32;
  const int gnb = n0 + wc * 32 * BNT;
#pragma unroll
  for (int nt = 0; nt < BNT; ++nt) {
    const int gn = gnb + nt * 32 + l31;
    const float bv = bias[gn];
#pragma unroll
    for (int mt = 0; mt < MT; ++mt)
#pragma unroll
      for (int r = 0; r < 16; ++r) {
        const int gm = gmb + mt * 32 + (r & 3) + 8 * (r >> 2) + 4 * hi;
        float v = acc[mt][nt][r] + bv;
        if (MODE == 1) {
          v = fmaxf(v, 0.f);
          Cb[(size_t)gm * N + gn] = f2bf(v);
        } else {
          Cf[(size_t)gm * N + gn] = v;
        }
      }
  }
}

// ---------------- bf16 MFMA flash attention, split-KV (2 splits) ----------------
// Grid 512: (bh, split, qt). Each block: 128 q rows, 1024 keys, 16 KV steps.
// Writes normalized bf16 partial O + (m,l) stats; combine kernel merges.
__global__ __launch_bounds__(256) void attn_mfma(const u16* __restrict__ qb,
                                                 const u16* __restrict__ kb,
                                                 const u16* __restrict__ vtb,
                                                 u16* __restrict__ pO,
                                                 float2* __restrict__ ml) {
  const int logical = ((blockIdx.x & 7) << 6) | (blockIdx.x >> 3);  // XCD swizzle (512=8*64)
  const int bh = logical >> 5;
  const int s  = (logical >> 4) & 1;
  const int qt = logical & 15;
  const int t = threadIdx.x;
  const int w = t >> 6, lane = t & 63;
  const int l31 = lane & 31, hi = lane >> 5;

  __shared__ u16 Kf[2][4096];
  __shared__ u16 Vf[2][4096];

  const size_t bh_off = (size_t)bh << 17;
  const int q0 = (qt << 7) + (w << 5);

  s16x8 qa[4];
  {
    const u16* qrow = qb + bh_off + (size_t)(q0 + l31) * 64 + hi * 8;
#pragma unroll
    for (int c = 0; c < 4; ++c) { B128 tmp; tmp.q = *(const uint4*)(qrow + c * 16); qa[c] = tmp.v; }
  }

  f32x16v ot0, ot1;
#pragma unroll
  for (int i = 0; i < 16; ++i) { ot0[i] = 0.f; ot1[i] = 0.f; }
  float mreg = -3e38f, lreg = 0.f;

  const int srow = t >> 2, scol = (t & 3) << 4;
  const int wb0 = (((((srow >> 5) << 2) + (t & 3)) << 6) + (srow & 31)) << 3;
  const u16* ksrc = kb + bh_off + (size_t)(s * 16) * 4096 + (size_t)srow * 64 + scol;
  const u16* vsrc = vtb + bh_off + (size_t)(s * 16) * 64 + (size_t)srow * 2048 + scol;

  {
    uint4 k0 = *(const uint4*)ksrc, k1 = *(const uint4*)(ksrc + 8);
    uint4 v0 = *(const uint4*)vsrc, v1 = *(const uint4*)(vsrc + 8);
    *(uint4*)&Kf[0][wb0] = k0; *(uint4*)&Kf[0][wb0 + 256] = k1;
    *(uint4*)&Vf[0][wb0] = v0; *(uint4*)&Vf[0][wb0 + 256] = v1;
  }
  __syncthreads();

  for (int jt = 0; jt < 16; ++jt) {
    const int cur = jt & 1;
    uint4 k0, k1, v0, v1;
    const bool more = (jt < 15);
    if (more) {
      const u16* kp = ksrc + (size_t)(jt + 1) * 4096;
      const u16* vp = vsrc + (size_t)(jt + 1) * 64;
      k0 = *(const uint4*)kp; k1 = *(const uint4*)(kp + 8);
      v0 = *(const uint4*)vp; v1 = *(const uint4*)(vp + 8);
    }

    f32x16v st0, st1;
#pragma unroll
    for (int i = 0; i < 16; ++i) { st0[i] = 0.f; st1[i] = 0.f; }
    __builtin_amdgcn_s_setprio(1);
#pragma unroll
    for (int c = 0; c < 4; ++c) {
      B128 kf0, kf1;
      kf0.q = *(const uint4*)&Kf[cur][(c * 64 + lane) * 8];
      kf1.q = *(const uint4*)&Kf[cur][((c + 4) * 64 + lane) * 8];
      st0 = __builtin_amdgcn_mfma_f32_32x32x16_bf16(kf0.v, qa[c], st0, 0, 0, 0);
      st1 = __builtin_amdgcn_mfma_f32_32x32x16_bf16(kf1.v, qa[c], st1, 0, 0, 0);
    }
    __builtin_amdgcn_s_setprio(0);

    // scores are in log2 units (QSCALE folds log2e); online softmax with defer-max (T13)
    float mx = -3e38f;
#pragma unroll
    for (int i = 0; i < 16; ++i) { mx = fmaxf(mx, st0[i]); mx = fmaxf(mx, st1[i]); }
    mx = fmaxf(mx, __shfl_xor(mx, 32));
    if (!__all(mx <= mreg + DEFER_THR)) {
      const float mnew = fmaxf(mreg, mx);
      const float sc = exp2f(mreg - mnew);
      lreg *= sc;
      ot0 *= sc; ot1 *= sc;
      mreg = mnew;
    }
    float pv[32];
    float ps = 0.f;
#pragma unroll
    for (int i = 0; i < 16; ++i) { pv[i] = exp2f(st0[i] - mreg); ps += pv[i]; }
#pragma unroll
    for (int i = 0; i < 16; ++i) { pv[16 + i] = exp2f(st1[i] - mreg); ps += pv[16 + i]; }
    ps += __shfl_xor(ps, 32);
    lreg += ps;

    u32 qp[2][4][2];
#pragma unroll
    for (int kt = 0; kt < 2; ++kt)
#pragma unroll
      for (int R = 0; R < 4; ++R) {
        qp[kt][R][0] = pk2trunc(pv[kt * 16 + R * 4 + 0], pv[kt * 16 + R * 4 + 1]);
        qp[kt][R][1] = pk2trunc(pv[kt * 16 + R * 4 + 2], pv[kt * 16 + R * 4 + 3]);
      }
    s16x8 pa[4];
#pragma unroll
    for (int kt = 0; kt < 2; ++kt)
#pragma unroll
      for (int cc = 0; cc < 2; ++cc) {
        const u32 a0 = qp[kt][2 * cc][0], a1 = qp[kt][2 * cc][1];
        const u32 b0 = qp[kt][2 * cc + 1][0], b1 = qp[kt][2 * cc + 1][1];
        const u32 xa0 = __shfl_xor(a0, 32), xa1 = __shfl_xor(a1, 32);
        const u32 xb0 = __shfl_xor(b0, 32), xb1 = __shfl_xor(b1, 32);
        B128 f;
        if (hi == 0) { f.u[0] = a0;  f.u[1] = a1;  f.u[2] = xa0; f.u[3] = xa1; }
        else         { f.u[0] = xb0; f.u[1] = xb1; f.u[2] = b0;  f.u[3] = b1;  }
        pa[kt * 2 + cc] = f.v;
      }

    __builtin_amdgcn_s_setprio(1);
#pragma unroll
    for (int c = 0; c < 4; ++c) {
      B128 vf0, vf1;
      vf0.q = *(const uint4*)&Vf[cur][(c * 64 + lane) * 8];
      vf1.q = *(const uint4*)&Vf[cur][((c + 4) * 64 + lane) * 8];
      ot0 = __builtin_amdgcn_mfma_f32_32x32x16_bf16(vf0.v, pa[c], ot0, 0, 0, 0);
      ot1 = __builtin_amdgcn_mfma_f32_32x32x16_bf16(vf1.v, pa[c], ot1, 0, 0, 0);
    }
    __builtin_amdgcn_s_setprio(0);

    if (more) {
      const int nb = cur ^ 1;
      *(uint4*)&Kf[nb][wb0] = k0; *(uint4*)&Kf[nb][wb0 + 256] = k1;
      *(uint4*)&Vf[nb][wb0] = v0; *(uint4*)&Vf[nb][wb0 + 256] = v1;
    }
    __syncthreads();
  }

  // write normalized bf16 partial + per-row stats (m in log2 units, l)
  const float linv = 1.f / lreg;
  u16* prow = pO + (((size_t)s * 16 + bh) * 2048 + q0 + l31) * 64;
#pragma unroll
  for (int R = 0; R < 4; ++R) {
    uint2 p0;
    p0.x = pk2rne(ot0[4 * R + 0] * linv, ot0[4 * R + 1] * linv);
    p0.y = pk2rne(ot0[4 * R + 2] * linv, ot0[4 * R + 3] * linv);
    *(uint2*)(prow + R * 8 + hi * 4) = p0;
    uint2 p1;
    p1.x = pk2rne(ot1[4 * R + 0] * linv, ot1[4 * R + 1] * linv);
    p1.y = pk2rne(ot1[4 * R + 2] * linv, ot1[4 * R + 3] * linv);
    *(uint2*)(prow + 32 + R * 8 + hi * 4) = p1;
  }
  if (hi == 0) ml[((size_t)s * 16 + bh) * 2048 + q0 + l31] = make_float2(mreg, lreg);
}

// ---- combine 2 splits: O = (w0*O0n + w1*O1n), wi = exp2(mi-M)*li / sum ----
__global__ __launch_bounds__(256) void attn_combine(const u16* __restrict__ pO,
                                                    const float2* __restrict__ ml,
                                                    float* __restrict__ attb) {
  const int tid = blockIdx.x * 256 + threadIdx.x;  // 131072
  const int row = tid >> 2;                        // bh*2048 + q
  const int seg = tid & 3;
  const float2 s0 = ml[row];
  const float2 s1 = ml[32768 + row];
  const float M = fmaxf(s0.x, s1.x);
  float w0 = exp2f(s0.x - M) * s0.y;
  float w1 = exp2f(s1.x - M) * s1.y;
  const float inv = 1.f / (w0 + w1);
  w0 *= inv; w1 *= inv;
  const u16* p0 = pO + (size_t)row * 64 + seg * 16;
  const u16* p1 = p0 + (size_t)32768 * 64;
  const int bh = row >> 11, q = row & 2047;
  float* dst = attb + ((size_t)(bh >> 3) * 2048 + q) * 512 + (bh & 7) * 64 + seg * 16;
  uint4 a0 = *(const uint4*)p0, a1 = *(const uint4*)(p0 + 8);
  uint4 b0 = *(const uint4*)p1, b1 = *(const uint4*)(p1 + 8);
  const u32 au[8] = { a0.x, a0.y, a0.z, a0.w, a1.x, a1.y, a1.z, a1.w };
  const u32 bu[8] = { b0.x, b0.y, b0.z, b0.w, b1.x, b1.y, b1.z, b1.w };
  float o[16];
#pragma unroll
  for (int i = 0; i < 8; ++i) {
    o[2 * i]     = w0 * bflo(au[i]) + w1 * bflo(bu[i]);
    o[2 * i + 1] = w0 * bfhi(au[i]) + w1 * bfhi(bu[i]);
  }
#pragma unroll
  for (int i = 0; i < 4; ++i)
    *(float4*)(dst + 4 * i) = make_float4(o[4 * i], o[4 * i + 1], o[4 * i + 2], o[4 * i + 3]);
}

// ---------------- fused residual add + LayerNorm; optional bf16 copy out ----------------
__global__ __launch_bounds__(256) void add_ln(const float* __restrict__ u,
                                              const float* __restrict__ v,
                                              const float* __restrict__ ga,
                                              const float* __restrict__ gb,
                                              float* __restrict__ out,
                                              u16* __restrict__ bfout) {
  const int row  = blockIdx.x * 4 + (threadIdx.x >> 6);
  const int lane = threadIdx.x & 63;
  const size_t base = (size_t)row * CD;
  float4 u0 = *(const float4*)(u + base + lane * 4);
  float4 v0 = *(const float4*)(v + base + lane * 4);
  float4 u1 = *(const float4*)(u + base + 256 + lane * 4);
  float4 v1 = *(const float4*)(v + base + 256 + lane * 4);
  float z[8] = { u0.x + v0.x, u0.y + v0.y, u0.z + v0.z, u0.w + v0.w,
                 u1.x + v1.x, u1.y + v1.y, u1.z + v1.z, u1.w + v1.w };
  float sum = 0.f, sq = 0.f;
#pragma unroll
  for (int i = 0; i < 8; ++i) { sum += z[i]; sq = fmaf(z[i], z[i], sq); }
#pragma unroll
  for (int off = 32; off > 0; off >>= 1) {
    sum += __shfl_xor(sum, off);
    sq  += __shfl_xor(sq, off);
  }
  float mean = sum * (1.f / CD);
  float var  = fmaxf((sq - (float)CD * mean * mean) * (1.f / (CD - 1)), 0.f);
  float inv  = 1.f / (sqrtf(var) + CEPS);
  float4 a0 = *(const float4*)(ga + lane * 4);
  float4 a1 = *(const float4*)(ga + 256 + lane * 4);
  float4 b0 = *(const float4*)(gb + lane * 4);
  float4 b1 = *(const float4*)(gb + 256 + lane * 4);
  float4 y0 = make_float4(fmaf((z[0] - mean) * inv, a0.x, b0.x),
                          fmaf((z[1] - mean) * inv, a0.y, b0.y),
                          fmaf((z[2] - mean) * inv, a0.z, b0.z),
                          fmaf((z[3] - mean) * inv, a0.w, b0.w));
  float4 y1 = make_float4(fmaf((z[4] - mean) * inv, a1.x, b1.x),
                          fmaf((z[5] - mean) * inv, a1.y, b1.y),
                          fmaf((z[6] - mean) * inv, a1.z, b1.z),
                          fmaf((z[7] - mean) * inv, a1.w, b1.w));
  *(float4*)(out + base + lane * 4)       = y0;
  *(float4*)(out + base + 256 + lane * 4) = y1;
  if (bfout) {
    uint2 p0; p0.x = pk2rne(y0.x, y0.y); p0.y = pk2rne(y0.z, y0.w);
    uint2 p1; p1.x = pk2rne(y1.x, y1.y); p1.y = pk2rne(y1.z, y1.w);
    *(uint2*)(bfout + base + lane * 4)       = p0;
    *(uint2*)(bfout + base + 256 + lane * 4) = p1;
  }
}

extern "C" void kernel_launch(void* const* d_in, const int* in_sizes, int n_in,
                              void* d_out, int out_size, void* d_ws, size_t ws_size,
                              hipStream_t stream) {
  (void)in_sizes; (void)n_in; (void)out_size; (void)ws_size;
  const float* x    = (const float*)d_in[0];
  const float* pos  = (const float*)d_in[1];
  const float* wq   = (const float*)d_in[2];
  const float* wk   = (const float*)d_in[3];
  const float* wv   = (const float*)d_in[4];
  const float* ln1a = (const float*)d_in[5];
  const float* ln1b = (const float*)d_in[6];
  const float* w1   = (const float*)d_in[7];
  const float* b1   = (const float*)d_in[8];
  const float* w2   = (const float*)d_in[9];
  const float* b2   = (const float*)d_in[10];
  const float* ln2a = (const float*)d_in[11];
  const float* ln2b = (const float*)d_in[12];

  float* ws = (float*)d_ws;
  float* xw  = ws;                    // 2M f32: residual stream
  float* x1  = xw + 2097152;          // 2M f32: LN1 out | pO partials (4M u16) during attn
  float* rA  = x1 + 2097152;          // 2M f32: attb (f32) | ff1b (4M u16)
  float* rB  = rA + 2097152;          // 2M f32: ff2 (f32) | qbuf+kbuf (4M u16)
  float* rC  = rB + 2097152;          // 1M f32: vtbuf (2M u16) | x1b (2M u16)
  float* rXb = rC + 1048576;          // 1M f32: xb (2M u16)
  float* rWq = rXb + 1048576;         // 786432 f32: wqkvb (1.57M u16)
  float* rW1 = rWq + 786432;          // 524288 f32: w1b
  float* rW2 = rW1 + 524288;          // 524288 f32: w2b
  float* rML = rW2 + 524288;          // 131072 f32: ml stats (65536 float2)  total 49.8 MB

  float* attb = rA;
  u16* ff1b  = (u16*)rA;
  float* ff2 = rB;
  u16* qbuf  = (u16*)rB;
  u16* kbuf  = qbuf + 2097152;
  u16* vtbuf = (u16*)rC;
  u16* x1b   = (u16*)rC;
  u16* xb    = (u16*)rXb;
  u16* wqkvb = (u16*)rWq;
  u16* w1b   = (u16*)rW1;
  u16* w2b   = (u16*)rW2;
  u16* pO    = (u16*)x1;
  float2* ml = (float2*)rML;

  repack_qkv<<<6144, 256, 0, stream>>>(wq, wk, wv, wqkvb);
  cast_bf16<<<1024, 256, 0, stream>>>((const float4*)w1, (uint2*)w1b);
  cast_bf16<<<1024, 256, 0, stream>>>((const float4*)w2, (uint2*)w2b);
  add_pos<<<2048, 256, 0, stream>>>((const float4*)x, (const float4*)pos,
                                    (float4*)xw, (uint2*)xb);

  for (int l = 0; l < CNL; ++l) {
    gemm_bf16<2, 1, 2><<<dim3(24, 32), 256, 0, stream>>>(
        xb, wqkvb + (size_t)l * 786432, nullptr, nullptr, qbuf, kbuf, vtbuf,
        4096, 1536, 512);
    attn_mfma<<<512, 256, 0, stream>>>(qbuf, kbuf, vtbuf, pO, ml);
    attn_combine<<<512, 256, 0, stream>>>(pO, ml, attb);
    add_ln<<<1024, 256, 0, stream>>>(attb, xw, ln1a + l * CD, ln1b + l * CD, x1, x1b);
    gemm_bf16<1, 1, 2><<<dim3(16, 32), 256, 0, stream>>>(
        x1b, w1b + (size_t)l * 524288, b1 + l * CDFF, nullptr, ff1b, nullptr, nullptr,
        4096, 1024, 512);
    gemm_bf16<0, 1, 1><<<dim3(8, 64), 256, 0, stream>>>(
        ff1b, w2b + (size_t)l * 524288, b2 + l * CD, ff2, nullptr, nullptr, nullptr,
        4096, 512, 1024);
    float* dst = (l == CNL - 1) ? (float*)d_out : xw;
    u16* bdst = (l == CNL - 1) ? nullptr : xb;
    add_ln<<<1024, 256, 0, stream>>>(ff2, x1, ln2a + l * CD, ln2b + l * CD, dst, bdst);
  }
}

// Round 8
// 427.876 us; speedup vs baseline: 5.1766x; 1.0116x over previous
//
#include <hip/hip_runtime.h>
#include <cstddef>
#include <cstdint>

typedef unsigned int u32;
typedef unsigned short u16;

constexpr int CB = 2, CL = 2048, CD = 512, CH = 8, CNL = 2, CDFF = 1024;
constexpr float CEPS = 1e-3f;
constexpr float INV_TEMPER = 0.044194173824159216f;   // 1/sqrt(512)
constexpr float QSCALE = INV_TEMPER * 1.4426950408889634f;  // fold log2e -> exp2 softmax
constexpr float DEFER_THR = 11.0f;                    // log2 units: p <= 2^11

typedef __attribute__((ext_vector_type(16))) float f32x16v;
typedef __attribute__((ext_vector_type(8))) short s16x8;

union B128 { s16x8 v; uint4 q; u32 u[4]; };

__device__ inline u16 f2bf(float f) {
  union { float f; u32 u; } x; x.f = f;
  u32 r = x.u + 0x7fffu + ((x.u >> 16) & 1u);
  return (u16)(r >> 16);
}
__device__ inline u32 pk2rne(float a, float b) {
  return (u32)f2bf(a) | ((u32)f2bf(b) << 16);
}
__device__ inline u32 pk2trunc(float a, float b) {
  union { float f; u32 u; } xa, xb; xa.f = a; xb.f = b;
  return (xa.u >> 16) | (xb.u & 0xffff0000u);
}
__device__ inline float bflo(u32 u) { union { u32 u; float f; } x; x.u = u << 16; return x.f; }
__device__ inline float bfhi(u32 u) { union { u32 u; float f; } x; x.u = u & 0xffff0000u; return x.f; }

// ---- repack wq/wk/wv (NL,H,D,DK) f32 -> (NL, 1536, D) bf16 (N,K); wq pre-scaled by QSCALE ----
__global__ __launch_bounds__(256) void repack_qkv(const float* __restrict__ wq,
                                                  const float* __restrict__ wk,
                                                  const float* __restrict__ wv,
                                                  u16* __restrict__ dst) {
  int i = blockIdx.x * 256 + threadIdx.x;
  int d = i & (CD - 1);
  int rest = i >> 9;
  int n = rest % 1536;
  int l = rest / 1536;
  int which = n >> 9;
  int r = n & 511;
  int hh = r >> 6;
  int kk = r & 63;
  const float* src = (which == 0) ? wq : (which == 1) ? wk : wv;
  float v = src[(((size_t)l * CH + hh) * CD + d) * 64 + kk];
  if (which == 0) v *= QSCALE;
  dst[i] = f2bf(v);
}

__global__ __launch_bounds__(256) void cast_bf16(const float4* __restrict__ in,
                                                 uint2* __restrict__ out) {
  int i = blockIdx.x * 256 + threadIdx.x;
  float4 v = in[i];
  uint2 p; p.x = pk2rne(v.x, v.y); p.y = pk2rne(v.z, v.w);
  out[i] = p;
}

__global__ __launch_bounds__(256) void add_pos(const float4* __restrict__ x,
                                               const float4* __restrict__ pos,
                                               float4* __restrict__ out,
                                               uint2* __restrict__ outb) {
  int i = blockIdx.x * 256 + threadIdx.x;
  float4 a = x[i];
  float4 p = pos[i & (CL * CD / 4 - 1)];
  float4 r = make_float4(a.x + p.x, a.y + p.y, a.z + p.z, a.w + p.w);
  out[i] = r;
  uint2 pk; pk.x = pk2rne(r.x, r.y); pk.y = pk2rne(r.z, r.w);
  outb[i] = pk;
}

// ---------------- bf16 MFMA GEMM: C[M,N] = A[M,K] * W[N,K]^T ----------------
// MODE 0: f32 out + bias. MODE 1: bf16 out + bias + relu. MODE 2: QKV epilogue.
// BM = 64*MT, BN = 64*BNT. 4 waves (2 m x 2 n); wave tile (32*MT) x (32*BNT). BK=64, dbuf.
// XCD-aware m-major swizzle: each XCD gets a contiguous (few m-panels x all n) chunk.
template<int MODE, int BNT, int MT>
__global__ __launch_bounds__(256) void gemm_bf16(const u16* __restrict__ A,
                                                 const u16* __restrict__ W,
                                                 const float* __restrict__ bias,
                                                 float* __restrict__ Cf,
                                                 u16* __restrict__ Cb,
                                                 u16* __restrict__ kbuf,
                                                 u16* __restrict__ vtbuf,
                                                 int M, int N, int K) {
  __shared__ u16 Asm[2][MT * 4096];
  __shared__ u16 Wsm[2][BNT * 4096];
  const int t = threadIdx.x;
  const int w = t >> 6, lane = t & 63;
  const int wr = w >> 1, wc = w & 1;
  const int l31 = lane & 31, hi = lane >> 5;

  // XCD swizzle (grids here are all divisible by 8): m-major logical id
  const int gx = gridDim.x;
  const int phys = blockIdx.y * gx + blockIdx.x;
  const int chunk = (gx * gridDim.y) >> 3;
  const int lid = (phys & 7) * chunk + (phys >> 3);
  const int m0 = (lid / gx) * (64 * MT), n0 = (lid % gx) * (64 * BNT);

  const int srow = t >> 3;          // 0..31
  const int scol = (t & 7) * 8;     // 0,8,..,56
  const u16* aglo = A + (size_t)(m0 + srow) * K + scol;
  const u16* wglo = W + (size_t)(n0 + srow) * K + scol;
  const int dbase = ((((t & 7) >> 1) * 64) + srow + ((t & 7) & 1) * 32) * 8;

  {  // prologue: stage k-tile 0 into buf 0
#pragma unroll
    for (int i = 0; i < 2 * MT; ++i)
      *(uint4*)&Asm[0][dbase + i * 2048] = *(const uint4*)(aglo + (size_t)(32 * i) * K);
#pragma unroll
    for (int i = 0; i < 2 * BNT; ++i)
      *(uint4*)&Wsm[0][dbase + i * 2048] = *(const uint4*)(wglo + (size_t)(32 * i) * K);
  }
  __syncthreads();

  f32x16v acc[MT][BNT];
#pragma unroll
  for (int mt = 0; mt < MT; ++mt)
#pragma unroll
    for (int nt = 0; nt < BNT; ++nt)
#pragma unroll
      for (int i = 0; i < 16; ++i) acc[mt][nt][i] = 0.f;

  const int nk = K >> 6;
  for (int kb = 0; kb < nk; ++kb) {
    const int cur = kb & 1;
    uint4 an[2 * MT], wn[2 * BNT];
    const bool more = (kb + 1 < nk);
    if (more) {
      const u16* ap = aglo + (kb + 1) * 64;
      const u16* wp = wglo + (kb + 1) * 64;
#pragma unroll
      for (int i = 0; i < 2 * MT; ++i) an[i] = *(const uint4*)(ap + (size_t)(32 * i) * K);
#pragma unroll
      for (int i = 0; i < 2 * BNT; ++i) wn[i] = *(const uint4*)(wp + (size_t)(32 * i) * K);
    }
    __builtin_amdgcn_s_setprio(1);
#pragma unroll
    for (int ks = 0; ks < 4; ++ks) {
      B128 af[MT], bf[BNT];
#pragma unroll
      for (int mt = 0; mt < MT; ++mt)
        af[mt].q = *(const uint4*)&Asm[cur][(((wr * MT + mt) * 4 + ks) * 64 + lane) * 8];
#pragma unroll
      for (int nt = 0; nt < BNT; ++nt)
        bf[nt].q = *(const uint4*)&Wsm[cur][(((wc * BNT + nt) * 4 + ks) * 64 + lane) * 8];
#pragma unroll
      for (int mt = 0; mt < MT; ++mt)
#pragma unroll
        for (int nt = 0; nt < BNT; ++nt)
          acc[mt][nt] = __builtin_amdgcn_mfma_f32_32x32x16_bf16(af[mt].v, bf[nt].v, acc[mt][nt], 0, 0, 0);
    }
    __builtin_amdgcn_s_setprio(0);
    if (more) {
      const int nb = cur ^ 1;
#pragma unroll
      for (int i = 0; i < 2 * MT; ++i) *(uint4*)&Asm[nb][dbase + i * 2048] = an[i];
#pragma unroll
      for (int i = 0; i < 2 * BNT; ++i) *(uint4*)&Wsm[nb][dbase + i * 2048] = wn[i];
    }
    __syncthreads();
  }

  if (MODE == 2) {
    const int region = n0 >> 9;          // BN=64 divides 512 boundaries: uniform per block
    const int bidx = m0 >> 11;
    const int lb0 = (m0 & 2047) + wr * MT * 32;
    const int bh = bidx * 8 + ((n0 & 511) >> 6);
    if (region <= 1) {
      const int dk = (wc * 32) + l31;    // BNT==1
      u16* qk = (region == 0 ? Cb : kbuf) + ((size_t)bh << 17) + dk;
#pragma unroll
      for (int mt = 0; mt < MT; ++mt)
#pragma unroll
        for (int r = 0; r < 16; ++r) {
          const int l = lb0 + mt * 32 + (r & 3) + 8 * (r >> 2) + 4 * hi;
          qk[(size_t)l * 64] = f2bf(acc[mt][0][r]);
        }
    } else {
      // V^T: LDS transpose (stride 136 pad) -> coalesced writes (256B contiguous per dk row)
      u16* tr = &Asm[0][0];              // 64*136 u16 = 8704 <= 16384 u16 available
      const int dk = (wc * 32) + l31;
#pragma unroll
      for (int mt = 0; mt < MT; ++mt)
#pragma unroll
        for (int R = 0; R < 4; ++R) {
          const int lloc = wr * MT * 32 + mt * 32 + 8 * R + 4 * hi;
          uint2 p;
          p.x = pk2rne(acc[mt][0][4 * R + 0], acc[mt][0][4 * R + 1]);
          p.y = pk2rne(acc[mt][0][4 * R + 2], acc[mt][0][4 * R + 3]);
          *(uint2*)&tr[dk * 136 + lloc] = p;
        }
      __syncthreads();
      const int row = t >> 2, seg = t & 3;
      u16* vb = vtbuf + ((size_t)(bh * 64 + row)) * 2048 + (m0 & 2047);
#pragma unroll
      for (int i = 0; i < 4; ++i) {
        const int off = i * 32 + seg * 8;              // uint4 = 8 u16: same offset both sides
        uint4 vv = *(const uint4*)&tr[row * 136 + off];
        *(uint4*)(vb + off) = vv;                      // 128 u16/row, fully contiguous
      }
    }
    return;
  }

  const int gmb = m0 + wr * MT * 32;
  const int gnb = n0 + wc * 32 * BNT;
#pragma unroll
  for (int nt = 0; nt < BNT; ++nt) {
    const int gn = gnb + nt * 32 + l31;
    const float bv = bias[gn];
#pragma unroll
    for (int mt = 0; mt < MT; ++mt)
#pragma unroll
      for (int r = 0; r < 16; ++r) {
        const int gm = gmb + mt * 32 + (r & 3) + 8 * (r >> 2) + 4 * hi;
        float v = acc[mt][nt][r] + bv;
        if (MODE == 1) {
          v = fmaxf(v, 0.f);
          Cb[(size_t)gm * N + gn] = f2bf(v);
        } else {
          Cf[(size_t)gm * N + gn] = v;
        }
      }
  }
}

// ---------------- bf16 MFMA flash attention, split-KV (2 splits) ----------------
__global__ __launch_bounds__(256) void attn_mfma(const u16* __restrict__ qb,
                                                 const u16* __restrict__ kb,
                                                 const u16* __restrict__ vtb,
                                                 u16* __restrict__ pO,
                                                 float2* __restrict__ ml) {
  const int logical = ((blockIdx.x & 7) << 6) | (blockIdx.x >> 3);  // XCD swizzle (512=8*64)
  const int bh = logical >> 5;
  const int s  = (logical >> 4) & 1;
  const int qt = logical & 15;
  const int t = threadIdx.x;
  const int w = t >> 6, lane = t & 63;
  const int l31 = lane & 31, hi = lane >> 5;

  __shared__ u16 Kf[2][4096];
  __shared__ u16 Vf[2][4096];

  const size_t bh_off = (size_t)bh << 17;
  const int q0 = (qt << 7) + (w << 5);

  s16x8 qa[4];
  {
    const u16* qrow = qb + bh_off + (size_t)(q0 + l31) * 64 + hi * 8;
#pragma unroll
    for (int c = 0; c < 4; ++c) { B128 tmp; tmp.q = *(const uint4*)(qrow + c * 16); qa[c] = tmp.v; }
  }

  f32x16v ot0, ot1;
#pragma unroll
  for (int i = 0; i < 16; ++i) { ot0[i] = 0.f; ot1[i] = 0.f; }
  float mreg = -3e38f, lreg = 0.f;

  const int srow = t >> 2, scol = (t & 3) << 4;
  const int wb0 = (((((srow >> 5) << 2) + (t & 3)) << 6) + (srow & 31)) << 3;
  const u16* ksrc = kb + bh_off + (size_t)(s * 16) * 4096 + (size_t)srow * 64 + scol;
  const u16* vsrc = vtb + bh_off + (size_t)(s * 16) * 64 + (size_t)srow * 2048 + scol;

  {
    uint4 k0 = *(const uint4*)ksrc, k1 = *(const uint4*)(ksrc + 8);
    uint4 v0 = *(const uint4*)vsrc, v1 = *(const uint4*)(vsrc + 8);
    *(uint4*)&Kf[0][wb0] = k0; *(uint4*)&Kf[0][wb0 + 256] = k1;
    *(uint4*)&Vf[0][wb0] = v0; *(uint4*)&Vf[0][wb0 + 256] = v1;
  }
  __syncthreads();

  for (int jt = 0; jt < 16; ++jt) {
    const int cur = jt & 1;
    uint4 k0, k1, v0, v1;
    const bool more = (jt < 15);
    if (more) {
      const u16* kp = ksrc + (size_t)(jt + 1) * 4096;
      const u16* vp = vsrc + (size_t)(jt + 1) * 64;
      k0 = *(const uint4*)kp; k1 = *(const uint4*)(kp + 8);
      v0 = *(const uint4*)vp; v1 = *(const uint4*)(vp + 8);
    }

    f32x16v st0, st1;
#pragma unroll
    for (int i = 0; i < 16; ++i) { st0[i] = 0.f; st1[i] = 0.f; }
    __builtin_amdgcn_s_setprio(1);
#pragma unroll
    for (int c = 0; c < 4; ++c) {
      B128 kf0, kf1;
      kf0.q = *(const uint4*)&Kf[cur][(c * 64 + lane) * 8];
      kf1.q = *(const uint4*)&Kf[cur][((c + 4) * 64 + lane) * 8];
      st0 = __builtin_amdgcn_mfma_f32_32x32x16_bf16(kf0.v, qa[c], st0, 0, 0, 0);
      st1 = __builtin_amdgcn_mfma_f32_32x32x16_bf16(kf1.v, qa[c], st1, 0, 0, 0);
    }
    __builtin_amdgcn_s_setprio(0);

    float mx = -3e38f;
#pragma unroll
    for (int i = 0; i < 16; ++i) { mx = fmaxf(mx, st0[i]); mx = fmaxf(mx, st1[i]); }
    mx = fmaxf(mx, __shfl_xor(mx, 32));
    if (!__all(mx <= mreg + DEFER_THR)) {
      const float mnew = fmaxf(mreg, mx);
      const float sc = exp2f(mreg - mnew);
      lreg *= sc;
      ot0 *= sc; ot1 *= sc;
      mreg = mnew;
    }
    float pv[32];
    float ps = 0.f;
#pragma unroll
    for (int i = 0; i < 16; ++i) { pv[i] = exp2f(st0[i] - mreg); ps += pv[i]; }
#pragma unroll
    for (int i = 0; i < 16; ++i) { pv[16 + i] = exp2f(st1[i] - mreg); ps += pv[16 + i]; }
    ps += __shfl_xor(ps, 32);
    lreg += ps;

    u32 qp[2][4][2];
#pragma unroll
    for (int kt = 0; kt < 2; ++kt)
#pragma unroll
      for (int R = 0; R < 4; ++R) {
        qp[kt][R][0] = pk2trunc(pv[kt * 16 + R * 4 + 0], pv[kt * 16 + R * 4 + 1]);
        qp[kt][R][1] = pk2trunc(pv[kt * 16 + R * 4 + 2], pv[kt * 16 + R * 4 + 3]);
      }
    s16x8 pa[4];
#pragma unroll
    for (int kt = 0; kt < 2; ++kt)
#pragma unroll
      for (int cc = 0; cc < 2; ++cc) {
        const u32 a0 = qp[kt][2 * cc][0], a1 = qp[kt][2 * cc][1];
        const u32 b0 = qp[kt][2 * cc + 1][0], b1 = qp[kt][2 * cc + 1][1];
        const u32 xa0 = __shfl_xor(a0, 32), xa1 = __shfl_xor(a1, 32);
        const u32 xb0 = __shfl_xor(b0, 32), xb1 = __shfl_xor(b1, 32);
        B128 f;
        if (hi == 0) { f.u[0] = a0;  f.u[1] = a1;  f.u[2] = xa0; f.u[3] = xa1; }
        else         { f.u[0] = xb0; f.u[1] = xb1; f.u[2] = b0;  f.u[3] = b1;  }
        pa[kt * 2 + cc] = f.v;
      }

    __builtin_amdgcn_s_setprio(1);
#pragma unroll
    for (int c = 0; c < 4; ++c) {
      B128 vf0, vf1;
      vf0.q = *(const uint4*)&Vf[cur][(c * 64 + lane) * 8];
      vf1.q = *(const uint4*)&Vf[cur][((c + 4) * 64 + lane) * 8];
      ot0 = __builtin_amdgcn_mfma_f32_32x32x16_bf16(vf0.v, pa[c], ot0, 0, 0, 0);
      ot1 = __builtin_amdgcn_mfma_f32_32x32x16_bf16(vf1.v, pa[c], ot1, 0, 0, 0);
    }
    __builtin_amdgcn_s_setprio(0);

    if (more) {
      const int nb = cur ^ 1;
      *(uint4*)&Kf[nb][wb0] = k0; *(uint4*)&Kf[nb][wb0 + 256] = k1;
      *(uint4*)&Vf[nb][wb0] = v0; *(uint4*)&Vf[nb][wb0 + 256] = v1;
    }
    __syncthreads();
  }

  const float linv = 1.f / lreg;
  u16* prow = pO + (((size_t)s * 16 + bh) * 2048 + q0 + l31) * 64;
#pragma unroll
  for (int R = 0; R < 4; ++R) {
    uint2 p0;
    p0.x = pk2rne(ot0[4 * R + 0] * linv, ot0[4 * R + 1] * linv);
    p0.y = pk2rne(ot0[4 * R + 2] * linv, ot0[4 * R + 3] * linv);
    *(uint2*)(prow + R * 8 + hi * 4) = p0;
    uint2 p1;
    p1.x = pk2rne(ot1[4 * R + 0] * linv, ot1[4 * R + 1] * linv);
    p1.y = pk2rne(ot1[4 * R + 2] * linv, ot1[4 * R + 3] * linv);
    *(uint2*)(prow + 32 + R * 8 + hi * 4) = p1;
  }
  if (hi == 0) ml[((size_t)s * 16 + bh) * 2048 + q0 + l31] = make_float2(mreg, lreg);
}

// ---- combine 2 splits ----
__global__ __launch_bounds__(256) void attn_combine(const u16* __restrict__ pO,
                                                    const float2* __restrict__ ml,
                                                    float* __restrict__ attb) {
  const int tid = blockIdx.x * 256 + threadIdx.x;  // 131072
  const int row = tid >> 2;                        // bh*2048 + q
  const int seg = tid & 3;
  const float2 s0 = ml[row];
  const float2 s1 = ml[32768 + row];
  const float M = fmaxf(s0.x, s1.x);
  float w0 = exp2f(s0.x - M) * s0.y;
  float w1 = exp2f(s1.x - M) * s1.y;
  const float inv = 1.f / (w0 + w1);
  w0 *= inv; w1 *= inv;
  const u16* p0 = pO + (size_t)row * 64 + seg * 16;
  const u16* p1 = p0 + (size_t)32768 * 64;
  const int bh = row >> 11, q = row & 2047;
  float* dst = attb + ((size_t)(bh >> 3) * 2048 + q) * 512 + (bh & 7) * 64 + seg * 16;
  uint4 a0 = *(const uint4*)p0, a1 = *(const uint4*)(p0 + 8);
  uint4 b0 = *(const uint4*)p1, b1 = *(const uint4*)(p1 + 8);
  const u32 au[8] = { a0.x, a0.y, a0.z, a0.w, a1.x, a1.y, a1.z, a1.w };
  const u32 bu[8] = { b0.x, b0.y, b0.z, b0.w, b1.x, b1.y, b1.z, b1.w };
  float o[16];
#pragma unroll
  for (int i = 0; i < 8; ++i) {
    o[2 * i]     = w0 * bflo(au[i]) + w1 * bflo(bu[i]);
    o[2 * i + 1] = w0 * bfhi(au[i]) + w1 * bfhi(bu[i]);
  }
#pragma unroll
  for (int i = 0; i < 4; ++i)
    *(float4*)(dst + 4 * i) = make_float4(o[4 * i], o[4 * i + 1], o[4 * i + 2], o[4 * i + 3]);
}

// ---------------- fused residual add + LayerNorm; optional bf16 copy out ----------------
__global__ __launch_bounds__(256) void add_ln(const float* __restrict__ u,
                                              const float* __restrict__ v,
                                              const float* __restrict__ ga,
                                              const float* __restrict__ gb,
                                              float* __restrict__ out,
                                              u16* __restrict__ bfout) {
  const int row  = blockIdx.x * 4 + (threadIdx.x >> 6);
  const int lane = threadIdx.x & 63;
  const size_t base = (size_t)row * CD;
  float4 u0 = *(const float4*)(u + base + lane * 4);
  float4 v0 = *(const float4*)(v + base + lane * 4);
  float4 u1 = *(const float4*)(u + base + 256 + lane * 4);
  float4 v1 = *(const float4*)(v + base + 256 + lane * 4);
  float z[8] = { u0.x + v0.x, u0.y + v0.y, u0.z + v0.z, u0.w + v0.w,
                 u1.x + v1.x, u1.y + v1.y, u1.z + v1.z, u1.w + v1.w };
  float sum = 0.f, sq = 0.f;
#pragma unroll
  for (int i = 0; i < 8; ++i) { sum += z[i]; sq = fmaf(z[i], z[i], sq); }
#pragma unroll
  for (int off = 32; off > 0; off >>= 1) {
    sum += __shfl_xor(sum, off);
    sq  += __shfl_xor(sq, off);
  }
  float mean = sum * (1.f / CD);
  float var  = fmaxf((sq - (float)CD * mean * mean) * (1.f / (CD - 1)), 0.f);
  float inv  = 1.f / (sqrtf(var) + CEPS);
  float4 a0 = *(const float4*)(ga + lane * 4);
  float4 a1 = *(const float4*)(ga + 256 + lane * 4);
  float4 b0 = *(const float4*)(gb + lane * 4);
  float4 b1 = *(const float4*)(gb + 256 + lane * 4);
  float4 y0 = make_float4(fmaf((z[0] - mean) * inv, a0.x, b0.x),
                          fmaf((z[1] - mean) * inv, a0.y, b0.y),
                          fmaf((z[2] - mean) * inv, a0.z, b0.z),
                          fmaf((z[3] - mean) * inv, a0.w, b0.w));
  float4 y1 = make_float4(fmaf((z[4] - mean) * inv, a1.x, b1.x),
                          fmaf((z[5] - mean) * inv, a1.y, b1.y),
                          fmaf((z[6] - mean) * inv, a1.z, b1.z),
                          fmaf((z[7] - mean) * inv, a1.w, b1.w));
  *(float4*)(out + base + lane * 4)       = y0;
  *(float4*)(out + base + 256 + lane * 4) = y1;
  if (bfout) {
    uint2 p0; p0.x = pk2rne(y0.x, y0.y); p0.y = pk2rne(y0.z, y0.w);
    uint2 p1; p1.x = pk2rne(y1.x, y1.y); p1.y = pk2rne(y1.z, y1.w);
    *(uint2*)(bfout + base + lane * 4)       = p0;
    *(uint2*)(bfout + base + 256 + lane * 4) = p1;
  }
}

extern "C" void kernel_launch(void* const* d_in, const int* in_sizes, int n_in,
                              void* d_out, int out_size, void* d_ws, size_t ws_size,
                              hipStream_t stream) {
  (void)in_sizes; (void)n_in; (void)out_size; (void)ws_size;
  const float* x    = (const float*)d_in[0];
  const float* pos  = (const float*)d_in[1];
  const float* wq   = (const float*)d_in[2];
  const float* wk   = (const float*)d_in[3];
  const float* wv   = (const float*)d_in[4];
  const float* ln1a = (const float*)d_in[5];
  const float* ln1b = (const float*)d_in[6];
  const float* w1   = (const float*)d_in[7];
  const float* b1   = (const float*)d_in[8];
  const float* w2   = (const float*)d_in[9];
  const float* b2   = (const float*)d_in[10];
  const float* ln2a = (const float*)d_in[11];
  const float* ln2b = (const float*)d_in[12];

  float* ws = (float*)d_ws;
  float* xw  = ws;                    // 2M f32: residual stream
  float* x1  = xw + 2097152;          // 2M f32: LN1 out | pO partials (4M u16) during attn
  float* rA  = x1 + 2097152;          // 2M f32: attb (f32) | ff1b (4M u16)
  float* rB  = rA + 2097152;          // 2M f32: ff2 (f32) | qbuf+kbuf (4M u16)
  float* rC  = rB + 2097152;          // 1M f32: vtbuf (2M u16) | x1b (2M u16)
  float* rXb = rC + 1048576;          // 1M f32: xb (2M u16)
  float* rWq = rXb + 1048576;         // 786432 f32: wqkvb (1.57M u16)
  float* rW1 = rWq + 786432;          // 524288 f32: w1b
  float* rW2 = rW1 + 524288;          // 524288 f32: w2b
  float* rML = rW2 + 524288;          // 131072 f32: ml stats (65536 float2)  total 49.8 MB

  float* attb = rA;
  u16* ff1b  = (u16*)rA;
  float* ff2 = rB;
  u16* qbuf  = (u16*)rB;
  u16* kbuf  = qbuf + 2097152;
  u16* vtbuf = (u16*)rC;
  u16* x1b   = (u16*)rC;
  u16* xb    = (u16*)rXb;
  u16* wqkvb = (u16*)rWq;
  u16* w1b   = (u16*)rW1;
  u16* w2b   = (u16*)rW2;
  u16* pO    = (u16*)x1;
  float2* ml = (float2*)rML;

  repack_qkv<<<6144, 256, 0, stream>>>(wq, wk, wv, wqkvb);
  cast_bf16<<<1024, 256, 0, stream>>>((const float4*)w1, (uint2*)w1b);
  cast_bf16<<<1024, 256, 0, stream>>>((const float4*)w2, (uint2*)w2b);
  add_pos<<<2048, 256, 0, stream>>>((const float4*)x, (const float4*)pos,
                                    (float4*)xw, (uint2*)xb);

  for (int l = 0; l < CNL; ++l) {
    gemm_bf16<2, 1, 2><<<dim3(24, 32), 256, 0, stream>>>(
        xb, wqkvb + (size_t)l * 786432, nullptr, nullptr, qbuf, kbuf, vtbuf,
        4096, 1536, 512);
    attn_mfma<<<512, 256, 0, stream>>>(qbuf, kbuf, vtbuf, pO, ml);
    attn_combine<<<512, 256, 0, stream>>>(pO, ml, attb);
    add_ln<<<1024, 256, 0, stream>>>(attb, xw, ln1a + l * CD, ln1b + l * CD, x1, x1b);
    gemm_bf16<1, 1, 2><<<dim3(16, 32), 256, 0, stream>>>(
        x1b, w1b + (size_t)l * 524288, b1 + l * CDFF, nullptr, ff1b, nullptr, nullptr,
        4096, 1024, 512);
    gemm_bf16<0, 1, 1><<<dim3(8, 64), 256, 0, stream>>>(
        ff1b, w2b + (size_t)l * 524288, b2 + l * CD, ff2, nullptr, nullptr, nullptr,
        4096, 512, 1024);
    float* dst = (l == CNL - 1) ? (float*)d_out : xw;
    u16* bdst = (l == CNL - 1) ? nullptr : xb;
    add_ln<<<1024, 256, 0, stream>>>(ff2, x1, ln2a + l * CD, ln2b + l * CD, dst, bdst);
  }
}

// Round 11
// 328.340 us; speedup vs baseline: 6.7459x; 1.3031x over previous
//
#include <hip/hip_runtime.h>
#include <cstddef>
#include <cstdint>

typedef unsigned int u32;
typedef unsigned short u16;

constexpr int CB = 2, CL = 2048, CD = 512, CH = 8, CNL = 2, CDFF = 1024;
constexpr float CEPS = 1e-3f;
constexpr float INV_TEMPER = 0.044194173824159216f;   // 1/sqrt(512)
constexpr float QSCALE = INV_TEMPER * 1.4426950408889634f;  // fold log2e -> exp2 softmax
constexpr float DEFER_THR = 11.0f;                    // log2 units

typedef __attribute__((ext_vector_type(16))) float f32x16v;
typedef __attribute__((ext_vector_type(8))) short s16x8;

union B128 { s16x8 v; uint4 q; u32 u[4]; };

__device__ inline u16 f2bf(float f) {
  union { float f; u32 u; } x; x.f = f;
  u32 r = x.u + 0x7fffu + ((x.u >> 16) & 1u);
  return (u16)(r >> 16);
}
__device__ inline u32 pk2rne(float a, float b) {
  return (u32)f2bf(a) | ((u32)f2bf(b) << 16);
}
__device__ inline u32 pk2trunc(float a, float b) {
  union { float f; u32 u; } xa, xb; xa.f = a; xb.f = b;
  return (xa.u >> 16) | (xb.u & 0xffff0000u);
}
__device__ inline float bflo(u32 u) { union { u32 u; float f; } x; x.u = u << 16; return x.f; }
__device__ inline float bfhi(u32 u) { union { u32 u; float f; } x; x.u = u & 0xffff0000u; return x.f; }

// async 16B/lane global -> LDS (dest = wave-uniform base + lane*16)
__device__ __forceinline__ void gload16(const u16* g, u16* l) {
  __builtin_amdgcn_global_load_lds(
      (const __attribute__((address_space(1))) u32*)(const void*)g,
      (__attribute__((address_space(3))) u32*)(void*)l, 16, 0, 0);
}

// ---- repack wq/wk/wv -> (NL, 1536, D) bf16 (N,K); wq pre-scaled by QSCALE ----
__global__ __launch_bounds__(256) void repack_qkv(const float* __restrict__ wq,
                                                  const float* __restrict__ wk,
                                                  const float* __restrict__ wv,
                                                  u16* __restrict__ dst) {
  int i = blockIdx.x * 256 + threadIdx.x;
  int d = i & (CD - 1);
  int rest = i >> 9;
  int n = rest % 1536;
  int l = rest / 1536;
  int which = n >> 9;
  int r = n & 511;
  int hh = r >> 6;
  int kk = r & 63;
  const float* src = (which == 0) ? wq : (which == 1) ? wk : wv;
  float v = src[(((size_t)l * CH + hh) * CD + d) * 64 + kk];
  if (which == 0) v *= QSCALE;
  dst[i] = f2bf(v);
}

__global__ __launch_bounds__(256) void cast_bf16_2(const float4* __restrict__ w1,
                                                   const float4* __restrict__ w2,
                                                   uint2* __restrict__ o1,
                                                   uint2* __restrict__ o2) {
  int i = blockIdx.x * 256 + threadIdx.x;   // 524288 = 2 x 262144
  if (i < 262144) {
    float4 v = w1[i];
    uint2 p; p.x = pk2rne(v.x, v.y); p.y = pk2rne(v.z, v.w);
    o1[i] = p;
  } else {
    int j = i - 262144;
    float4 v = w2[j];
    uint2 p; p.x = pk2rne(v.x, v.y); p.y = pk2rne(v.z, v.w);
    o2[j] = p;
  }
}

__global__ __launch_bounds__(256) void add_pos(const float4* __restrict__ x,
                                               const float4* __restrict__ pos,
                                               float4* __restrict__ out,
                                               uint2* __restrict__ outb) {
  int i = blockIdx.x * 256 + threadIdx.x;
  float4 a = x[i];
  float4 p = pos[i & (CL * CD / 4 - 1)];
  float4 r = make_float4(a.x + p.x, a.y + p.y, a.z + p.z, a.w + p.w);
  out[i] = r;
  uint2 pk; pk.x = pk2rne(r.x, r.y); pk.y = pk2rne(r.z, r.w);
  outb[i] = pk;
}

// ---------------- bf16 MFMA GEMM: C[M,N] = A[M,K] * W[N,K]^T ----------------
// MODE 0: f32 out + bias. MODE 1: bf16 out + bias + relu. MODE 2: QKV epilogue.
// BM=64*MT, BN=64*BNT. 4 waves (2m x 2n). BK=64. 2-phase global_load_lds pipeline:
// frag-linear LDS (frag f at offset f*512 u16; lane's 8 u16 at +lane*8) is exactly
// gload_lds's linear dest order -> zero staging ds_writes, zero bank conflicts.
template<int MODE, int BNT, int MT>
__global__ __launch_bounds__(256) void gemm_bf16(const u16* __restrict__ A,
                                                 const u16* __restrict__ W,
                                                 const float* __restrict__ bias,
                                                 float* __restrict__ Cf,
                                                 u16* __restrict__ Cb,
                                                 u16* __restrict__ kbuf,
                                                 u16* __restrict__ vtbuf,
                                                 int M, int N, int K) {
  __shared__ u16 Asm[2][MT * 4096];
  __shared__ u16 Wsm[2][BNT * 4096];
  const int t = threadIdx.x;
  const int w = t >> 6, lane = t & 63;
  const int wr = w >> 1, wc = w & 1;
  const int l31 = lane & 31, hi = lane >> 5;

  // XCD-aware m-major swizzle (grids divisible by 8)
  const int gx = gridDim.x;
  const int phys = blockIdx.y * gx + blockIdx.x;
  const int chunk = (gx * gridDim.y) >> 3;
  const int lid = (phys & 7) * chunk + (phys >> 3);
  const int m0 = (lid / gx) * (64 * MT), n0 = (lid % gx) * (64 * BNT);

  // per-wave async staging: nf frags/wave; A frags [0,8*MT), B frags [0,8*BNT)
  const int nf = 2 * (MT + BNT);
  auto stage = [&](int kt, int buf) {
#pragma unroll
    for (int j = 0; j < nf; ++j) {
      const int fid = w * nf + j;
      if (fid < 8 * MT) {
        const u16* src = A + (size_t)(m0 + (fid >> 2) * 32 + l31) * K
                         + kt * 64 + (fid & 3) * 16 + hi * 8;
        gload16(src, &Asm[buf][fid * 512]);
      } else {
        const int fb = fid - 8 * MT;
        const u16* src = W + (size_t)(n0 + (fb >> 2) * 32 + l31) * K
                         + kt * 64 + (fb & 3) * 16 + hi * 8;
        gload16(src, &Wsm[buf][fb * 512]);
      }
    }
  };

  stage(0, 0);
  __syncthreads();

  f32x16v acc[MT][BNT];
#pragma unroll
  for (int mt = 0; mt < MT; ++mt)
#pragma unroll
    for (int nt = 0; nt < BNT; ++nt)
#pragma unroll
      for (int i = 0; i < 16; ++i) acc[mt][nt][i] = 0.f;

  const int nk = K >> 6;
  for (int kb = 0; kb < nk; ++kb) {
    const int cur = kb & 1;
    if (kb + 1 < nk) stage(kb + 1, cur ^ 1);
    __builtin_amdgcn_s_setprio(1);
#pragma unroll
    for (int ks = 0; ks < 4; ++ks) {
      B128 af[MT], bf[BNT];
#pragma unroll
      for (int mt = 0; mt < MT; ++mt)
        af[mt].q = *(const uint4*)&Asm[cur][(((wr * MT + mt) * 4 + ks) * 64 + lane) * 8];
#pragma unroll
      for (int nt = 0; nt < BNT; ++nt)
        bf[nt].q = *(const uint4*)&Wsm[cur][(((wc * BNT + nt) * 4 + ks) * 64 + lane) * 8];
#pragma unroll
      for (int mt = 0; mt < MT; ++mt)
#pragma unroll
        for (int nt = 0; nt < BNT; ++nt)
          acc[mt][nt] = __builtin_amdgcn_mfma_f32_32x32x16_bf16(af[mt].v, bf[nt].v, acc[mt][nt], 0, 0, 0);
    }
    __builtin_amdgcn_s_setprio(0);
    __syncthreads();   // drains gload_lds queue (vmcnt(0) before s_barrier) + frees cur
  }

  if (MODE == 2) {
    const int region = n0 >> 9;
    const int bidx = m0 >> 11;
    const int lb0 = (m0 & 2047) + wr * MT * 32;
    const int bh = bidx * 8 + ((n0 & 511) >> 6);
    if (region <= 1) {
      const int dk = (wc * 32) + l31;    // BNT==1
      u16* qk = (region == 0 ? Cb : kbuf) + ((size_t)bh << 17) + dk;
#pragma unroll
      for (int mt = 0; mt < MT; ++mt)
#pragma unroll
        for (int r = 0; r < 16; ++r) {
          const int l = lb0 + mt * 32 + (r & 3) + 8 * (r >> 2) + 4 * hi;
          qk[(size_t)l * 64] = f2bf(acc[mt][0][r]);
        }
    } else {
      // V^T via LDS transpose (stride 136) -> 256B-contiguous global writes
      u16* tr = &Asm[0][0];
      const int dk = (wc * 32) + l31;
#pragma unroll
      for (int mt = 0; mt < MT; ++mt)
#pragma unroll
        for (int R = 0; R < 4; ++R) {
          const int lloc = wr * MT * 32 + mt * 32 + 8 * R + 4 * hi;
          uint2 p;
          p.x = pk2rne(acc[mt][0][4 * R + 0], acc[mt][0][4 * R + 1]);
          p.y = pk2rne(acc[mt][0][4 * R + 2], acc[mt][0][4 * R + 3]);
          *(uint2*)&tr[dk * 136 + lloc] = p;
        }
      __syncthreads();
      const int row = t >> 2, seg = t & 3;
      u16* vb = vtbuf + ((size_t)(bh * 64 + row)) * 2048 + (m0 & 2047);
#pragma unroll
      for (int i = 0; i < 4; ++i) {
        const int off = i * 32 + seg * 8;
        uint4 vv = *(const uint4*)&tr[row * 136 + off];
        *(uint4*)(vb + off) = vv;
      }
    }
    return;
  }

  const int gmb = m0 + wr * MT * 32;
  const int gnb = n0 + wc * 32 * BNT;
#pragma unroll
  for (int nt = 0; nt < BNT; ++nt) {
    const int gn = gnb + nt * 32 + l31;
    const float bv = bias[gn];
#pragma unroll
    for (int mt = 0; mt < MT; ++mt)
#pragma unroll
      for (int r = 0; r < 16; ++r) {
        const int gm = gmb + mt * 32 + (r & 3) + 8 * (r >> 2) + 4 * hi;
        float v = acc[mt][nt][r] + bv;
        if (MODE == 1) {
          v = fmaxf(v, 0.f);
          Cb[(size_t)gm * N + gn] = f2bf(v);
        } else {
          Cf[(size_t)gm * N + gn] = v;
        }
      }
  }
}

// ---------------- bf16 MFMA flash attention, split-KV (2 splits), gload_lds staging ----
__global__ __launch_bounds__(256) void attn_mfma(const u16* __restrict__ qb,
                                                 const u16* __restrict__ kb,
                                                 const u16* __restrict__ vtb,
                                                 u16* __restrict__ pO,
                                                 float2* __restrict__ ml) {
  const int logical = ((blockIdx.x & 7) << 6) | (blockIdx.x >> 3);  // XCD swizzle
  const int bh = logical >> 5;
  const int s  = (logical >> 4) & 1;
  const int qt = logical & 15;
  const int t = threadIdx.x;
  const int w = t >> 6, lane = t & 63;
  const int l31 = lane & 31, hi = lane >> 5;

  __shared__ u16 Kf[2][4096];
  __shared__ u16 Vf[2][4096];

  const size_t bh_off = (size_t)bh << 17;
  const int q0 = (qt << 7) + (w << 5);

  // per-wave async staging: 4 frags/wave (8 K-frags + 8 V-frags total)
  auto stageKV = [&](int kt, int buf) {
#pragma unroll
    for (int j = 0; j < 4; ++j) {
      const int fid = w * 4 + j;
      if (fid < 8) {
        const int c = fid;
        const u16* src = kb + bh_off
            + (size_t)(s * 1024 + kt * 64 + (c >> 2) * 32 + l31) * 64
            + (c & 3) * 16 + hi * 8;
        gload16(src, &Kf[buf][c * 512]);
      } else {
        const int c = fid - 8;
        const u16* src = vtb + bh_off
            + (size_t)((c >> 2) * 32 + l31) * 2048
            + s * 1024 + kt * 64 + (c & 3) * 16 + hi * 8;
        gload16(src, &Vf[buf][c * 512]);
      }
    }
  };

  s16x8 qa[4];
  {
    const u16* qrow = qb + bh_off + (size_t)(q0 + l31) * 64 + hi * 8;
#pragma unroll
    for (int c = 0; c < 4; ++c) { B128 tmp; tmp.q = *(const uint4*)(qrow + c * 16); qa[c] = tmp.v; }
  }

  f32x16v ot0, ot1;
#pragma unroll
  for (int i = 0; i < 16; ++i) { ot0[i] = 0.f; ot1[i] = 0.f; }
  float mreg = -3e38f, lreg = 0.f;

  stageKV(0, 0);
  __syncthreads();

  for (int jt = 0; jt < 16; ++jt) {
    const int cur = jt & 1;
    if (jt < 15) stageKV(jt + 1, cur ^ 1);

    f32x16v st0, st1;
#pragma unroll
    for (int i = 0; i < 16; ++i) { st0[i] = 0.f; st1[i] = 0.f; }
    __builtin_amdgcn_s_setprio(1);
#pragma unroll
    for (int c = 0; c < 4; ++c) {
      B128 kf0, kf1;
      kf0.q = *(const uint4*)&Kf[cur][(c * 64 + lane) * 8];
      kf1.q = *(const uint4*)&Kf[cur][((c + 4) * 64 + lane) * 8];
      st0 = __builtin_amdgcn_mfma_f32_32x32x16_bf16(kf0.v, qa[c], st0, 0, 0, 0);
      st1 = __builtin_amdgcn_mfma_f32_32x32x16_bf16(kf1.v, qa[c], st1, 0, 0, 0);
    }
    __builtin_amdgcn_s_setprio(0);

    float mx = -3e38f;
#pragma unroll
    for (int i = 0; i < 16; ++i) { mx = fmaxf(mx, st0[i]); mx = fmaxf(mx, st1[i]); }
    mx = fmaxf(mx, __shfl_xor(mx, 32));
    if (!__all(mx <= mreg + DEFER_THR)) {
      const float mnew = fmaxf(mreg, mx);
      const float sc = exp2f(mreg - mnew);
      lreg *= sc;
      ot0 *= sc; ot1 *= sc;
      mreg = mnew;
    }
    float pv[32];
    float ps = 0.f;
#pragma unroll
    for (int i = 0; i < 16; ++i) { pv[i] = exp2f(st0[i] - mreg); ps += pv[i]; }
#pragma unroll
    for (int i = 0; i < 16; ++i) { pv[16 + i] = exp2f(st1[i] - mreg); ps += pv[16 + i]; }
    ps += __shfl_xor(ps, 32);
    lreg += ps;

    u32 qp[2][4][2];
#pragma unroll
    for (int kt = 0; kt < 2; ++kt)
#pragma unroll
      for (int R = 0; R < 4; ++R) {
        qp[kt][R][0] = pk2trunc(pv[kt * 16 + R * 4 + 0], pv[kt * 16 + R * 4 + 1]);
        qp[kt][R][1] = pk2trunc(pv[kt * 16 + R * 4 + 2], pv[kt * 16 + R * 4 + 3]);
      }
    s16x8 pa[4];
#pragma unroll
    for (int kt = 0; kt < 2; ++kt)
#pragma unroll
      for (int cc = 0; cc < 2; ++cc) {
        const u32 a0 = qp[kt][2 * cc][0], a1 = qp[kt][2 * cc][1];
        const u32 b0 = qp[kt][2 * cc + 1][0], b1 = qp[kt][2 * cc + 1][1];
        const u32 xa0 = __shfl_xor(a0, 32), xa1 = __shfl_xor(a1, 32);
        const u32 xb0 = __shfl_xor(b0, 32), xb1 = __shfl_xor(b1, 32);
        B128 f;
        if (hi == 0) { f.u[0] = a0;  f.u[1] = a1;  f.u[2] = xa0; f.u[3] = xa1; }
        else         { f.u[0] = xb0; f.u[1] = xb1; f.u[2] = b0;  f.u[3] = b1;  }
        pa[kt * 2 + cc] = f.v;
      }

    __builtin_amdgcn_s_setprio(1);
#pragma unroll
    for (int c = 0; c < 4; ++c) {
      B128 vf0, vf1;
      vf0.q = *(const uint4*)&Vf[cur][(c * 64 + lane) * 8];
      vf1.q = *(const uint4*)&Vf[cur][((c + 4) * 64 + lane) * 8];
      ot0 = __builtin_amdgcn_mfma_f32_32x32x16_bf16(vf0.v, pa[c], ot0, 0, 0, 0);
      ot1 = __builtin_amdgcn_mfma_f32_32x32x16_bf16(vf1.v, pa[c], ot1, 0, 0, 0);
    }
    __builtin_amdgcn_s_setprio(0);
    __syncthreads();
  }

  const float linv = 1.f / lreg;
  u16* prow = pO + (((size_t)s * 16 + bh) * 2048 + q0 + l31) * 64;
#pragma unroll
  for (int R = 0; R < 4; ++R) {
    uint2 p0;
    p0.x = pk2rne(ot0[4 * R + 0] * linv, ot0[4 * R + 1] * linv);
    p0.y = pk2rne(ot0[4 * R + 2] * linv, ot0[4 * R + 3] * linv);
    *(uint2*)(prow + R * 8 + hi * 4) = p0;
    uint2 p1;
    p1.x = pk2rne(ot1[4 * R + 0] * linv, ot1[4 * R + 1] * linv);
    p1.y = pk2rne(ot1[4 * R + 2] * linv, ot1[4 * R + 3] * linv);
    *(uint2*)(prow + 32 + R * 8 + hi * 4) = p1;
  }
  if (hi == 0) ml[((size_t)s * 16 + bh) * 2048 + q0 + l31] = make_float2(mreg, lreg);
}

// ---- fused split-combine + residual add + LayerNorm (LN1) ----
__global__ __launch_bounds__(256) void add_ln_att(const u16* __restrict__ pO,
                                                  const float2* __restrict__ ml,
                                                  const float* __restrict__ resid,
                                                  const float* __restrict__ ga,
                                                  const float* __restrict__ gb,
                                                  float* __restrict__ out,
                                                  u16* __restrict__ bfout) {
  const int row  = blockIdx.x * 4 + (threadIdx.x >> 6);  // b*2048+q
  const int lane = threadIdx.x & 63;
  const int b = row >> 11, q = row & 2047;
  const int h = lane >> 3;
  const int bh = b * 8 + h;
  const float2 s0 = ml[(size_t)bh * 2048 + q];
  const float2 s1 = ml[(size_t)(16 + bh) * 2048 + q];
  const float M = fmaxf(s0.x, s1.x);
  float w0 = exp2f(s0.x - M) * s0.y;
  float w1 = exp2f(s1.x - M) * s1.y;
  const float inv0 = 1.f / (w0 + w1);
  w0 *= inv0; w1 *= inv0;
  const size_t prow = ((size_t)bh * 2048 + q) * 64 + (lane & 7) * 8;
  uint4 a = *(const uint4*)(pO + prow);
  uint4 c = *(const uint4*)(pO + (size_t)2097152 + prow);  // split 1
  const u32 au[4] = { a.x, a.y, a.z, a.w };
  const u32 cu[4] = { c.x, c.y, c.z, c.w };
  const size_t base = (size_t)row * CD;
  float4 r0 = *(const float4*)(resid + base + lane * 8);
  float4 r1 = *(const float4*)(resid + base + lane * 8 + 4);
  const float rr[8] = { r0.x, r0.y, r0.z, r0.w, r1.x, r1.y, r1.z, r1.w };
  float z[8];
#pragma unroll
  for (int i = 0; i < 4; ++i) {
    z[2 * i]     = w0 * bflo(au[i]) + w1 * bflo(cu[i]) + rr[2 * i];
    z[2 * i + 1] = w0 * bfhi(au[i]) + w1 * bfhi(cu[i]) + rr[2 * i + 1];
  }
  float sum = 0.f, sq = 0.f;
#pragma unroll
  for (int i = 0; i < 8; ++i) { sum += z[i]; sq = fmaf(z[i], z[i], sq); }
#pragma unroll
  for (int off = 32; off > 0; off >>= 1) {
    sum += __shfl_xor(sum, off);
    sq  += __shfl_xor(sq, off);
  }
  float mean = sum * (1.f / CD);
  float var  = fmaxf((sq - (float)CD * mean * mean) * (1.f / (CD - 1)), 0.f);
  float inv  = 1.f / (sqrtf(var) + CEPS);
  float4 a0 = *(const float4*)(ga + lane * 8);
  float4 a1 = *(const float4*)(ga + lane * 8 + 4);
  float4 b0 = *(const float4*)(gb + lane * 8);
  float4 b1 = *(const float4*)(gb + lane * 8 + 4);
  float4 y0 = make_float4(fmaf((z[0] - mean) * inv, a0.x, b0.x),
                          fmaf((z[1] - mean) * inv, a0.y, b0.y),
                          fmaf((z[2] - mean) * inv, a0.z, b0.z),
                          fmaf((z[3] - mean) * inv, a0.w, b0.w));
  float4 y1 = make_float4(fmaf((z[4] - mean) * inv, a1.x, b1.x),
                          fmaf((z[5] - mean) * inv, a1.y, b1.y),
                          fmaf((z[6] - mean) * inv, a1.z, b1.z),
                          fmaf((z[7] - mean) * inv, a1.w, b1.w));
  *(float4*)(out + base + lane * 8)     = y0;
  *(float4*)(out + base + lane * 8 + 4) = y1;
  if (bfout) {
    uint2 p0; p0.x = pk2rne(y0.x, y0.y); p0.y = pk2rne(y0.z, y0.w);
    uint2 p1; p1.x = pk2rne(y1.x, y1.y); p1.y = pk2rne(y1.z, y1.w);
    *(uint2*)(bfout + base + lane * 8)     = p0;
    *(uint2*)(bfout + base + lane * 8 + 4) = p1;
  }
}

// ---------------- fused residual add + LayerNorm (LN2) ----------------
__global__ __launch_bounds__(256) void add_ln(const float* __restrict__ u,
                                              const float* __restrict__ v,
                                              const float* __restrict__ ga,
                                              const float* __restrict__ gb,
                                              float* __restrict__ out,
                                              u16* __restrict__ bfout) {
  const int row  = blockIdx.x * 4 + (threadIdx.x >> 6);
  const int lane = threadIdx.x & 63;
  const size_t base = (size_t)row * CD;
  float4 u0 = *(const float4*)(u + base + lane * 4);
  float4 v0 = *(const float4*)(v + base + lane * 4);
  float4 u1 = *(const float4*)(u + base + 256 + lane * 4);
  float4 v1 = *(const float4*)(v + base + 256 + lane * 4);
  float z[8] = { u0.x + v0.x, u0.y + v0.y, u0.z + v0.z, u0.w + v0.w,
                 u1.x + v1.x, u1.y + v1.y, u1.z + v1.z, u1.w + v1.w };
  float sum = 0.f, sq = 0.f;
#pragma unroll
  for (int i = 0; i < 8; ++i) { sum += z[i]; sq = fmaf(z[i], z[i], sq); }
#pragma unroll
  for (int off = 32; off > 0; off >>= 1) {
    sum += __shfl_xor(sum, off);
    sq  += __shfl_xor(sq, off);
  }
  float mean = sum * (1.f / CD);
  float var  = fmaxf((sq - (float)CD * mean * mean) * (1.f / (CD - 1)), 0.f);
  float inv  = 1.f / (sqrtf(var) + CEPS);
  float4 a0 = *(const float4*)(ga + lane * 4);
  float4 a1 = *(const float4*)(ga + 256 + lane * 4);
  float4 b0 = *(const float4*)(gb + lane * 4);
  float4 b1 = *(const float4*)(gb + 256 + lane * 4);
  float4 y0 = make_float4(fmaf((z[0] - mean) * inv, a0.x, b0.x),
                          fmaf((z[1] - mean) * inv, a0.y, b0.y),
                          fmaf((z[2] - mean) * inv, a0.z, b0.z),
                          fmaf((z[3] - mean) * inv, a0.w, b0.w));
  float4 y1 = make_float4(fmaf((z[4] - mean) * inv, a1.x, b1.x),
                          fmaf((z[5] - mean) * inv, a1.y, b1.y),
                          fmaf((z[6] - mean) * inv, a1.z, b1.z),
                          fmaf((z[7] - mean) * inv, a1.w, b1.w));
  *(float4*)(out + base + lane * 4)       = y0;
  *(float4*)(out + base + 256 + lane * 4) = y1;
  if (bfout) {
    uint2 p0; p0.x = pk2rne(y0.x, y0.y); p0.y = pk2rne(y0.z, y0.w);
    uint2 p1; p1.x = pk2rne(y1.x, y1.y); p1.y = pk2rne(y1.z, y1.w);
    *(uint2*)(bfout + base + lane * 4)       = p0;
    *(uint2*)(bfout + base + 256 + lane * 4) = p1;
  }
}

extern "C" void kernel_launch(void* const* d_in, const int* in_sizes, int n_in,
                              void* d_out, int out_size, void* d_ws, size_t ws_size,
                              hipStream_t stream) {
  (void)in_sizes; (void)n_in; (void)out_size; (void)ws_size;
  const float* x    = (const float*)d_in[0];
  const float* pos  = (const float*)d_in[1];
  const float* wq   = (const float*)d_in[2];
  const float* wk   = (const float*)d_in[3];
  const float* wv   = (const float*)d_in[4];
  const float* ln1a = (const float*)d_in[5];
  const float* ln1b = (const float*)d_in[6];
  const float* w1   = (const float*)d_in[7];
  const float* b1   = (const float*)d_in[8];
  const float* w2   = (const float*)d_in[9];
  const float* b2   = (const float*)d_in[10];
  const float* ln2a = (const float*)d_in[11];
  const float* ln2b = (const float*)d_in[12];

  float* ws = (float*)d_ws;
  float* xw  = ws;                    // 2M f32: residual stream
  float* x1  = xw + 2097152;          // 2M f32: LN1 out
  float* rA  = x1 + 2097152;          // 2M f32: pO partials (4M u16) during attn | ff1b (4M u16)
  float* rB  = rA + 2097152;          // 2M f32: ff2 (f32) | qbuf+kbuf (4M u16)
  float* rC  = rB + 2097152;          // 1M f32: vtbuf (2M u16) | x1b (2M u16)
  float* rXb = rC + 1048576;          // 1M f32: xb (2M u16)
  float* rWq = rXb + 1048576;         // wqkvb (1.57M u16)
  float* rW1 = rWq + 786432;          // w1b
  float* rW2 = rW1 + 524288;          // w2b
  float* rML = rW2 + 524288;          // ml stats (65536 float2)

  u16* ff1b  = (u16*)rA;
  float* ff2 = rB;
  u16* qbuf  = (u16*)rB;
  u16* kbuf  = qbuf + 2097152;
  u16* vtbuf = (u16*)rC;
  u16* x1b   = (u16*)rC;
  u16* xb    = (u16*)rXb;
  u16* wqkvb = (u16*)rWq;
  u16* w1b   = (u16*)rW1;
  u16* w2b   = (u16*)rW2;
  u16* pO    = (u16*)rA;   // RACE FIX: pO no longer aliases x1 (add_ln_att's output);
                           // rA is dead during attn+add_ln_att (ff1b written after)
  float2* ml = (float2*)rML;

  repack_qkv<<<6144, 256, 0, stream>>>(wq, wk, wv, wqkvb);
  cast_bf16_2<<<2048, 256, 0, stream>>>((const float4*)w1, (const float4*)w2,
                                        (uint2*)w1b, (uint2*)w2b);
  add_pos<<<2048, 256, 0, stream>>>((const float4*)x, (const float4*)pos,
                                    (float4*)xw, (uint2*)xb);

  for (int l = 0; l < CNL; ++l) {
    gemm_bf16<2, 1, 2><<<dim3(24, 32), 256, 0, stream>>>(
        xb, wqkvb + (size_t)l * 786432, nullptr, nullptr, qbuf, kbuf, vtbuf,
        4096, 1536, 512);
    attn_mfma<<<512, 256, 0, stream>>>(qbuf, kbuf, vtbuf, pO, ml);
    add_ln_att<<<1024, 256, 0, stream>>>(pO, ml, xw, ln1a + l * CD, ln1b + l * CD, x1, x1b);
    gemm_bf16<1, 1, 2><<<dim3(16, 32), 256, 0, stream>>>(
        x1b, w1b + (size_t)l * 524288, b1 + l * CDFF, nullptr, ff1b, nullptr, nullptr,
        4096, 1024, 512);
    gemm_bf16<0, 1, 1><<<dim3(8, 64), 256, 0, stream>>>(
        ff1b, w2b + (size_t)l * 524288, b2 + l * CD, ff2, nullptr, nullptr, nullptr,
        4096, 512, 1024);
    float* dst = (l == CNL - 1) ? (float*)d_out : xw;
    u16* bdst = (l == CNL - 1) ? nullptr : xb;
    add_ln<<<1024, 256, 0, stream>>>(ff2, x1, ln2a + l * CD, ln2b + l * CD, dst, bdst);
  }
}